// Round 1
// baseline (1038.907 us; speedup 1.0000x reference)
//
#include <hip/hip_runtime.h>
#include <stdint.h>

// ---------- types ----------
typedef __attribute__((ext_vector_type(8))) short bf16x8;   // 8 bf16 in 4 VGPRs
typedef __attribute__((ext_vector_type(4))) float f32x4;

__device__ __forceinline__ float bf2f(short u){
  union { float f; uint32_t i; } v; v.i = ((uint32_t)(uint16_t)u) << 16; return v.f;
}
__device__ __forceinline__ short f2bf(float x){
  union { float f; uint32_t i; } v; v.f = x;
  uint32_t r = v.i + 0x7FFFu + ((v.i >> 16) & 1u);   // RNE
  return (short)(r >> 16);
}

// ---------- permutation tables (WIN=7, compile-time) ----------
__device__ const int d_DIAG[49] = {0,1,7,2,8,14,3,9,15,21,4,10,16,22,28,5,11,17,23,29,35,
  6,12,18,24,30,36,42,13,19,25,31,37,43,20,26,32,38,44,27,33,39,45,34,40,46,41,47,48};
__device__ const int d_ANTI[49] = {6,5,13,4,12,20,3,11,19,27,2,10,18,26,34,1,9,17,25,33,41,
  0,8,16,24,32,40,48,7,15,23,31,39,47,14,22,30,38,46,21,29,37,45,28,36,44,35,43,42};

__device__ __forceinline__ int perm_idx(int g, int l){
  if (g == 0) return l;
  if (g == 1) return (l % 7) * 7 + l / 7;  // V_IDX
  if (g == 2) return d_DIAG[l];
  return d_ANTI[l];
}

// ---------- tiny prep kernels ----------
__global__ __launch_bounds__(512) void k_gains(const float* __restrict__ gl,
    const float* __restrict__ pb0, const float* __restrict__ pb1,
    const float* __restrict__ pb2, const float* __restrict__ pb3,
    float* __restrict__ gains, float* __restrict__ biasc)
{
  float m = fmaxf(fmaxf(gl[0], gl[1]), fmaxf(gl[2], gl[3]));
  float e0 = expf(gl[0]-m), e1 = expf(gl[1]-m), e2 = expf(gl[2]-m), e3 = expf(gl[3]-m);
  float s = e0+e1+e2+e3;
  float g0 = e0/s, g1 = e1/s, g2 = e2/s, g3 = e3/s;
  int t = threadIdx.x;
  if (t == 0){ gains[0]=g0; gains[1]=g1; gains[2]=g2; gains[3]=g3; }
  biasc[t] = g0*pb0[t] + g1*pb1[t] + g2*pb2[t] + g3*pb3[t];
}

__global__ __launch_bounds__(256) void k_tok(const float* __restrict__ t, short* __restrict__ o){
  int i = (blockIdx.x*256 + threadIdx.x) * 4;
  float4 v = *(const float4*)(t + i);
  uint32_t p0 = (uint32_t)(uint16_t)f2bf(v.x) | ((uint32_t)(uint16_t)f2bf(v.y) << 16);
  uint32_t p1 = (uint32_t)(uint16_t)f2bf(v.z) | ((uint32_t)(uint16_t)f2bf(v.w) << 16);
  uint2 p; p.x = p0; p.y = p1;
  *(uint2*)(o + i) = p;
}

// convert/transpose all weights: in_proj(bf16), out_proj^T(bf16), post(bf16), pre^T(bf16)
__global__ __launch_bounds__(256) void k_wpack(
    const float* __restrict__ in_proj, const float* __restrict__ out_proj,
    const float* __restrict__ pw0, const float* __restrict__ pw1,
    const float* __restrict__ pw2, const float* __restrict__ pw3,
    const float* __restrict__ qw0, const float* __restrict__ qw1,
    const float* __restrict__ qw2, const float* __restrict__ qw3,
    short* __restrict__ inp_bf, short* __restrict__ postw_bf,
    short* __restrict__ woutT, short* __restrict__ wpreT)
{
  int i = blockIdx.x*256 + threadIdx.x;           // 0 .. 2621439
  if (i < 262144){ inp_bf[i] = f2bf(in_proj[i]); return; }
  i -= 262144;
  if (i < 262144){                                 // out_proj transpose
    int j = i >> 9, t = i & 511;
    woutT[t*512 + j] = f2bf(out_proj[i]);
    return;
  }
  i -= 262144;
  if (i < 1048576){                                // post weights plain convert
    const float* p = (i < 524288) ? ((i < 262144) ? pw0 : pw1)
                                  : ((i < 786432) ? pw2 : pw3);
    postw_bf[i] = f2bf(p[i & 262143]);
    return;
  }
  i -= 1048576;
  {                                                // pre weights transpose
    int g = i >> 18; int r = i & 262143;
    const float* p = (g==0)?qw0:(g==1)?qw1:(g==2)?qw2:qw3;
    int j = r & 511, t = r >> 9;
    wpreT[g*262144 + j*512 + t] = f2bf(p[r]);
  }
}

// b_xz[g][i] = sum_t in_proj[i][t] * pre_b_g[t]
__global__ __launch_bounds__(256) void k_bxz(const float* __restrict__ in_proj,
    const float* __restrict__ b0, const float* __restrict__ b1,
    const float* __restrict__ b2, const float* __restrict__ b3,
    float* __restrict__ bxz)
{
  int idx = blockIdx.x*256 + threadIdx.x;   // 0..2047
  int g = idx >> 9, i = idx & 511;
  const float* bb = (g==0)?b0:(g==1)?b1:(g==2)?b2:b3;
  float s = 0.f;
  for (int t=0;t<512;t++) s += in_proj[i*512+t]*bb[t];
  bxz[idx] = s;
}

// ---------- shared MFMA core: wave computes 32(M) x 64(N), K multiple of 32 ----------
__device__ __forceinline__ void mfma_2x4_k(const short* a0, const short* a1,
    const short* b0, const short* b1, const short* b2, const short* b3,
    int K, f32x4 acc[2][4])
{
  for (int k0 = 0; k0 < K; k0 += 32){
    bf16x8 av0 = *(const bf16x8*)(a0 + k0);
    bf16x8 av1 = *(const bf16x8*)(a1 + k0);
    bf16x8 bv0 = *(const bf16x8*)(b0 + k0);
    bf16x8 bv1 = *(const bf16x8*)(b1 + k0);
    bf16x8 bv2 = *(const bf16x8*)(b2 + k0);
    bf16x8 bv3 = *(const bf16x8*)(b3 + k0);
    acc[0][0] = __builtin_amdgcn_mfma_f32_16x16x32_bf16(av0, bv0, acc[0][0],0,0,0);
    acc[0][1] = __builtin_amdgcn_mfma_f32_16x16x32_bf16(av0, bv1, acc[0][1],0,0,0);
    acc[0][2] = __builtin_amdgcn_mfma_f32_16x16x32_bf16(av0, bv2, acc[0][2],0,0,0);
    acc[0][3] = __builtin_amdgcn_mfma_f32_16x16x32_bf16(av0, bv3, acc[0][3],0,0,0);
    acc[1][0] = __builtin_amdgcn_mfma_f32_16x16x32_bf16(av1, bv0, acc[1][0],0,0,0);
    acc[1][1] = __builtin_amdgcn_mfma_f32_16x16x32_bf16(av1, bv1, acc[1][1],0,0,0);
    acc[1][2] = __builtin_amdgcn_mfma_f32_16x16x32_bf16(av1, bv2, acc[1][2],0,0,0);
    acc[1][3] = __builtin_amdgcn_mfma_f32_16x16x32_bf16(av1, bv3, acc[1][3],0,0,0);
  }
}

// ---------- W_xz[g] = in_proj @ pre_w_g   (512x512, K=512) ----------
__global__ __launch_bounds__(256) void k_wfuseW(const short* __restrict__ inp_bf,
    const short* __restrict__ wpreT, short* __restrict__ wxz)
{
  int g = blockIdx.z;
  int bn = blockIdx.x * 64, bm = blockIdx.y * 128;
  int lane = threadIdx.x & 63, wave = threadIdx.x >> 6;
  int mr = lane & 15, qk = (lane >> 4) * 8, quad = lane >> 4;
  const short* Bg = wpreT + g*262144;
  const short* a0 = inp_bf + (bm + wave*32 + mr)*512 + qk;
  const short* a1 = a0 + 16*512;
  const short* b0 = Bg + (bn +  0 + mr)*512 + qk;
  const short* b1 = Bg + (bn + 16 + mr)*512 + qk;
  const short* b2 = Bg + (bn + 32 + mr)*512 + qk;
  const short* b3 = Bg + (bn + 48 + mr)*512 + qk;
  f32x4 acc[2][4] = {};
  mfma_2x4_k(a0, a1, b0, b1, b2, b3, 512, acc);
  short* Cg = wxz + g*262144;
  #pragma unroll
  for (int s=0;s<2;s++)
    #pragma unroll
    for (int t=0;t<4;t++)
      #pragma unroll
      for (int r=0;r<4;r++){
        int row = bm + wave*32 + s*16 + quad*4 + r;
        int col = bn + t*16 + mr;
        Cg[row*512 + col] = f2bf(acc[s][t][r]);
      }
}

// ---------- Wog[g] = gain_g * (post_w_g @ out_proj_w), packed [n][g*512+t] ----------
__global__ __launch_bounds__(256) void k_wfuse2(const short* __restrict__ postw_bf,
    const short* __restrict__ woutT, const float* __restrict__ gains,
    short* __restrict__ wogc)
{
  int g = blockIdx.z;
  int bn = blockIdx.x * 64, bm = blockIdx.y * 128;
  int lane = threadIdx.x & 63, wave = threadIdx.x >> 6;
  int mr = lane & 15, qk = (lane >> 4) * 8, quad = lane >> 4;
  const short* Ag = postw_bf + g*262144;
  const short* a0 = Ag + (bm + wave*32 + mr)*512 + qk;
  const short* a1 = a0 + 16*512;
  const short* b0 = woutT + (bn +  0 + mr)*512 + qk;
  const short* b1 = woutT + (bn + 16 + mr)*512 + qk;
  const short* b2 = woutT + (bn + 32 + mr)*512 + qk;
  const short* b3 = woutT + (bn + 48 + mr)*512 + qk;
  f32x4 acc[2][4] = {};
  mfma_2x4_k(a0, a1, b0, b1, b2, b3, 512, acc);
  float gain = gains[g];
  #pragma unroll
  for (int s=0;s<2;s++)
    #pragma unroll
    for (int t=0;t<4;t++)
      #pragma unroll
      for (int r=0;r<4;r++){
        int row = bm + wave*32 + s*16 + quad*4 + r;
        int col = bn + t*16 + mr;
        wogc[row*2048 + g*512 + col] = f2bf(gain * acc[s][t][r]);
      }
}

// ---------- GEMM1: xz[(g*512+b)*49+l][ch] = tok[b][perm_g(l)][:] @ W_xz[g]^T + b_xz[g] ----------
__global__ __launch_bounds__(256) void k_gemm1(const short* __restrict__ tok,
    const short* __restrict__ wxz, const float* __restrict__ bxz, short* __restrict__ xz)
{
  int g = blockIdx.z;
  int bn = blockIdx.x * 64, bm = blockIdx.y * 128;   // bm over 25088 rows (b*49+l)
  int lane = threadIdx.x & 63, wave = threadIdx.x >> 6;
  int mr = lane & 15, qk = (lane >> 4) * 8, quad = lane >> 4;
  const short* Bg = wxz + g*262144;
  const short* ap[2];
  #pragma unroll
  for (int s=0;s<2;s++){
    int rowg = bm + wave*32 + s*16 + mr;
    int b = rowg / 49, l = rowg - b*49;
    int sl = perm_idx(g, l);
    ap[s] = tok + (b*49 + sl)*512 + qk;
  }
  const short* b0 = Bg + (bn +  0 + mr)*512 + qk;
  const short* b1 = Bg + (bn + 16 + mr)*512 + qk;
  const short* b2 = Bg + (bn + 32 + mr)*512 + qk;
  const short* b3 = Bg + (bn + 48 + mr)*512 + qk;
  f32x4 acc[2][4] = {};
  mfma_2x4_k(ap[0], ap[1], b0, b1, b2, b3, 512, acc);
  #pragma unroll
  for (int s=0;s<2;s++)
    #pragma unroll
    for (int r=0;r<4;r++){
      int rowg = bm + wave*32 + s*16 + quad*4 + r;
      int b = rowg / 49, l = rowg - b*49;
      size_t orow = ((size_t)(g*512 + b)*49 + l) * 512;
      #pragma unroll
      for (int t=0;t<4;t++){
        int col = bn + t*16 + mr;
        xz[orow + col] = f2bf(acc[s][t][r] + bxz[g*512 + col]);
      }
    }
}

// ---------- stage B: conv -> SiLU -> x_proj(MFMA) -> LN -> dt -> scan -> y_concat ----------
__global__ __launch_bounds__(256) void k_stageB(const short* __restrict__ xz,
    const float* __restrict__ cxw, const float* __restrict__ cxb,
    const float* __restrict__ czw, const float* __restrict__ czb,
    const float* __restrict__ xpw, const float* __restrict__ lnw, const float* __restrict__ lnb,
    const float* __restrict__ dtw, const float* __restrict__ dtb,
    const float* __restrict__ Alog, const float* __restrict__ Dp,
    short* __restrict__ ycat)
{
  // LDS layout (bytes): [0,25088) xconv bf16 rows 0..48 (rows 49..63 read-only pad
  // aliasing xdbl -> feeds only discarded MFMA output rows); [25088,34496) xdbl f32 49x48;
  // [34496,59072) xpw bf16 48x256.
  __shared__ __align__(16) char smem[59072];
  short* xconv_s = (short*)smem;
  float* xdbl    = (float*)(smem + 25088);
  short* xpw_s   = (short*)(smem + 34496);

  int gb = blockIdx.x;
  int d  = threadIdx.x;           // 0..255 == channel
  const short* xzb = xz + (size_t)gb * 25088;     // 49*512
  short* yb = ycat + (size_t)gb * 25088;

  // x depthwise conv (k=3, SAME) + SiLU -> LDS (bf16)
  {
    float w0 = cxw[d*3], w1 = cxw[d*3+1], w2 = cxw[d*3+2], bb = cxb[d];
    float vm = 0.f, v0 = bf2f(xzb[d]);
    for (int l=0;l<49;l++){
      float vp = (l<48) ? bf2f(xzb[(l+1)*512 + d]) : 0.f;
      float c = w0*vm + w1*v0 + w2*vp + bb;
      xconv_s[l*256 + d] = f2bf(c / (1.f + __expf(-c)));
      vm = v0; v0 = vp;
    }
  }
  // z depthwise conv + SiLU -> straight to y_concat channels 256..511
  {
    float w0 = czw[d*3], w1 = czw[d*3+1], w2 = czw[d*3+2], bb = czb[d];
    float vm = 0.f, v0 = bf2f(xzb[256 + d]);
    for (int l=0;l<49;l++){
      float vp = (l<48) ? bf2f(xzb[(l+1)*512 + 256 + d]) : 0.f;
      float c = w0*vm + w1*v0 + w2*vp + bb;
      yb[l*512 + 256 + d] = f2bf(c / (1.f + __expf(-c)));
      vm = v0; v0 = vp;
    }
  }
  // stage x_proj_w into LDS as bf16
  for (int i = d; i < 12288; i += 256) xpw_s[i] = f2bf(xpw[i]);
  __syncthreads();

  // x_dbl[l][e] = sum_d xconv[l][d] * xpw[e][d]  via MFMA (M=64 padded, N=48, K=256)
  {
    int lane = d & 63, wave = d >> 6;
    int mr = lane & 15, qk = (lane >> 4) * 8, quad = lane >> 4;
    const short* ar = xconv_s + (wave*16 + mr)*256 + qk;
    f32x4 accp[3] = {};
    #pragma unroll
    for (int k0 = 0; k0 < 256; k0 += 32){
      bf16x8 a = *(const bf16x8*)(ar + k0);
      #pragma unroll
      for (int t=0;t<3;t++){
        bf16x8 b = *(const bf16x8*)(xpw_s + (t*16 + mr)*256 + qk + k0);
        accp[t] = __builtin_amdgcn_mfma_f32_16x16x32_bf16(a, b, accp[t],0,0,0);
      }
    }
    #pragma unroll
    for (int t=0;t<3;t++)
      #pragma unroll
      for (int r=0;r<4;r++){
        int row = wave*16 + quad*4 + r;
        if (row < 49) xdbl[row*48 + t*16 + mr] = accp[t][r];
      }
  }
  __syncthreads();

  // layernorm over E=48, one thread per l
  if (d < 49){
    float m = 0.f;
    for (int e=0;e<48;e++) m += xdbl[d*48+e];
    m *= (1.f/48.f);
    float v = 0.f;
    for (int e=0;e<48;e++){ float t = xdbl[d*48+e]-m; v += t*t; }
    v *= (1.f/48.f);
    float r = rsqrtf(v + 1e-5f);
    for (int e=0;e<48;e++) xdbl[d*48+e] = (xdbl[d*48+e]-m)*r*lnw[e] + lnb[e];
  }
  __syncthreads();

  // selective scan (f32), one thread per channel d
  {
    float A[8], h[8];
    #pragma unroll
    for (int n=0;n<8;n++){ A[n] = -__expf(Alog[d*8+n]); h[n] = 0.f; }
    float Dpar = Dp[d], dtbias = dtb[d];
    float w[32];
    #pragma unroll
    for (int r=0;r<32;r++) w[r] = dtw[d*32+r];
    for (int l=0;l<49;l++){
      const float* xr = xdbl + l*48;
      float dtv = dtbias;
      #pragma unroll
      for (int r=0;r<32;r++) dtv += xr[r]*w[r];
      float delta = (dtv > 20.f) ? dtv : log1pf(__expf(dtv));
      float u = bf2f(xconv_s[l*256 + d]);
      float y = 0.f;
      #pragma unroll
      for (int n=0;n<8;n++){
        float dA = __expf(delta * A[n]);
        h[n] = h[n]*dA + delta * xr[32+n] * u;
        y += h[n] * xr[40+n];
      }
      yb[l*512 + d] = f2bf(y + Dpar*u);
    }
  }
}

// ---------- final GEMM: out[b*49+l][n] = sum_g ycat[g-slice] @ Wogc + biasc (K=2048) ----------
__global__ __launch_bounds__(256) void k_gemmF(const short* __restrict__ ycat,
    const short* __restrict__ wogc, const float* __restrict__ biasc,
    float* __restrict__ out)
{
  int bn = blockIdx.x * 64, bm = blockIdx.y * 128;  // bm over 25088 rows (b*49+l)
  int lane = threadIdx.x & 63, wave = threadIdx.x >> 6;
  int mr = lane & 15, qk = (lane >> 4) * 8, quad = lane >> 4;
  // ycat row for group kg is kg*25088 + rowg  (rowg = b*49+l)
  const short* a0 = ycat + (size_t)(bm + wave*32 +  0 + mr)*512 + qk;
  const short* a1 = ycat + (size_t)(bm + wave*32 + 16 + mr)*512 + qk;
  const short* b0 = wogc + (bn +  0 + mr)*2048 + qk;
  const short* b1 = wogc + (bn + 16 + mr)*2048 + qk;
  const short* b2 = wogc + (bn + 32 + mr)*2048 + qk;
  const short* b3 = wogc + (bn + 48 + mr)*2048 + qk;
  f32x4 acc[2][4] = {};
  #pragma unroll 1
  for (int kg=0; kg<4; kg++){
    size_t aoff = (size_t)kg * 12845056;   // 25088*512
    int boff = kg * 512;
    mfma_2x4_k(a0 + aoff, a1 + aoff, b0 + boff, b1 + boff, b2 + boff, b3 + boff, 512, acc);
  }
  #pragma unroll
  for (int s=0;s<2;s++)
    #pragma unroll
    for (int r=0;r<4;r++){
      int rowg = bm + wave*32 + s*16 + quad*4 + r;
      float* orow = out + (size_t)rowg*512;
      #pragma unroll
      for (int t=0;t<4;t++){
        int col = bn + t*16 + mr;
        orow[col] = acc[s][t][r] + biasc[col];
      }
    }
}

// ---------- launch ----------
extern "C" void kernel_launch(void* const* d_in, const int* in_sizes, int n_in,
                              void* d_out, int out_size, void* d_ws, size_t ws_size,
                              hipStream_t stream)
{
  const float* tokens    = (const float*)d_in[0];
  const float* pre_w[4]  = {(const float*)d_in[1], (const float*)d_in[3], (const float*)d_in[5], (const float*)d_in[7]};
  const float* pre_b[4]  = {(const float*)d_in[2], (const float*)d_in[4], (const float*)d_in[6], (const float*)d_in[8]};
  const float* post_w[4] = {(const float*)d_in[9], (const float*)d_in[11], (const float*)d_in[13], (const float*)d_in[15]};
  const float* post_b[4] = {(const float*)d_in[10], (const float*)d_in[12], (const float*)d_in[14], (const float*)d_in[16]};
  const float* in_proj   = (const float*)d_in[17];
  const float* conv_x_w  = (const float*)d_in[18];
  const float* conv_x_b  = (const float*)d_in[19];
  const float* conv_z_w  = (const float*)d_in[20];
  const float* conv_z_b  = (const float*)d_in[21];
  const float* x_proj_w  = (const float*)d_in[22];
  const float* ln_w      = (const float*)d_in[23];
  const float* ln_b      = (const float*)d_in[24];
  const float* dt_proj_w = (const float*)d_in[25];
  const float* dt_proj_b = (const float*)d_in[26];
  const float* A_log     = (const float*)d_in[27];
  const float* D_param   = (const float*)d_in[28];
  const float* out_proj  = (const float*)d_in[29];
  const float* gate_log  = (const float*)d_in[30];

  char* ws = (char*)d_ws;
  size_t o = 0;
  short* tok_bf   = (short*)(ws + o); o += 25690112;   // 12845056 bf16
  short* wpreT    = (short*)(ws + o); o += 2097152;    // 4x 512x512 bf16 (transposed)
  short* inp_bf   = (short*)(ws + o); o += 524288;
  short* postw_bf = (short*)(ws + o); o += 2097152;
  short* woutT    = (short*)(ws + o); o += 524288;
  short* wogc     = (short*)(ws + o); o += 2097152;    // 512 x 2048 bf16
  short* wxz      = (short*)(ws + o); o += 2097152;    // 4x 512x512 bf16
  float* bxz      = (float*)(ws + o); o += 8192;
  float* gains    = (float*)(ws + o); o += 64;
  float* biasc    = (float*)(ws + o); o += 2048;
  short* xz       = (short*)(ws + o); o += 102760448;  // 2048*49*512 bf16
  short* ycat     = (short*)(ws + o); o += 102760448;

  k_gains<<<1, 512, 0, stream>>>(gate_log, post_b[0], post_b[1], post_b[2], post_b[3], gains, biasc);
  k_tok<<<12544, 256, 0, stream>>>(tokens, tok_bf);
  k_wpack<<<10240, 256, 0, stream>>>(in_proj, out_proj,
      post_w[0], post_w[1], post_w[2], post_w[3],
      pre_w[0], pre_w[1], pre_w[2], pre_w[3],
      inp_bf, postw_bf, woutT, wpreT);
  k_bxz<<<8, 256, 0, stream>>>(in_proj, pre_b[0], pre_b[1], pre_b[2], pre_b[3], bxz);
  k_wfuseW<<<dim3(8,4,4), 256, 0, stream>>>(inp_bf, wpreT, wxz);
  k_wfuse2<<<dim3(8,4,4), 256, 0, stream>>>(postw_bf, woutT, gains, wogc);
  k_gemm1<<<dim3(8,196,4), 256, 0, stream>>>(tok_bf, wxz, bxz, xz);
  k_stageB<<<2048, 256, 0, stream>>>(xz, conv_x_w, conv_x_b, conv_z_w, conv_z_b,
      x_proj_w, ln_w, ln_b, dt_proj_w, dt_proj_b, A_log, D_param, ycat);
  k_gemmF<<<dim3(8,196,1), 256, 0, stream>>>(ycat, wogc, biasc, (float*)d_out);
}

// Round 2
// 742.136 us; speedup vs baseline: 1.3999x; 1.3999x over previous
//
#include <hip/hip_runtime.h>
#include <stdint.h>

// ---------- types ----------
typedef __attribute__((ext_vector_type(8))) short bf16x8;   // 8 bf16 in 4 VGPRs
typedef __attribute__((ext_vector_type(4))) float f32x4;

__device__ __forceinline__ float bf2f(short u){
  union { float f; uint32_t i; } v; v.i = ((uint32_t)(uint16_t)u) << 16; return v.f;
}
__device__ __forceinline__ short f2bf(float x){
  union { float f; uint32_t i; } v; v.f = x;
  uint32_t r = v.i + 0x7FFFu + ((v.i >> 16) & 1u);   // RNE
  return (short)(r >> 16);
}

// async global->LDS, 16B per lane; LDS dest = wave-uniform base + lane*16
__device__ __forceinline__ void gl_lds16(const short* g, short* l){
  __builtin_amdgcn_global_load_lds(
      (__attribute__((address_space(1))) void*)(short*)g,
      (__attribute__((address_space(3))) void*)l, 16, 0, 0);
}

// ---------- permutation tables (WIN=7, compile-time) ----------
__device__ const int d_DIAG[49] = {0,1,7,2,8,14,3,9,15,21,4,10,16,22,28,5,11,17,23,29,35,
  6,12,18,24,30,36,42,13,19,25,31,37,43,20,26,32,38,44,27,33,39,45,34,40,46,41,47,48};
__device__ const int d_ANTI[49] = {6,5,13,4,12,20,3,11,19,27,2,10,18,26,34,1,9,17,25,33,41,
  0,8,16,24,32,40,48,7,15,23,31,39,47,14,22,30,38,46,21,29,37,45,28,36,44,35,43,42};

__device__ __forceinline__ int perm_idx(int g, int l){
  if (g == 0) return l;
  if (g == 1) return (l % 7) * 7 + l / 7;  // V_IDX
  if (g == 2) return d_DIAG[l];
  return d_ANTI[l];
}

// ---------- tiny prep kernels ----------
__global__ __launch_bounds__(512) void k_gains(const float* __restrict__ gl,
    const float* __restrict__ pb0, const float* __restrict__ pb1,
    const float* __restrict__ pb2, const float* __restrict__ pb3,
    float* __restrict__ gains, float* __restrict__ biasc)
{
  float m = fmaxf(fmaxf(gl[0], gl[1]), fmaxf(gl[2], gl[3]));
  float e0 = expf(gl[0]-m), e1 = expf(gl[1]-m), e2 = expf(gl[2]-m), e3 = expf(gl[3]-m);
  float s = e0+e1+e2+e3;
  float g0 = e0/s, g1 = e1/s, g2 = e2/s, g3 = e3/s;
  int t = threadIdx.x;
  if (t == 0){ gains[0]=g0; gains[1]=g1; gains[2]=g2; gains[3]=g3; }
  biasc[t] = g0*pb0[t] + g1*pb1[t] + g2*pb2[t] + g3*pb3[t];
}

__global__ __launch_bounds__(256) void k_tok(const float* __restrict__ t, short* __restrict__ o){
  int i = (blockIdx.x*256 + threadIdx.x) * 4;
  float4 v = *(const float4*)(t + i);
  uint32_t p0 = (uint32_t)(uint16_t)f2bf(v.x) | ((uint32_t)(uint16_t)f2bf(v.y) << 16);
  uint32_t p1 = (uint32_t)(uint16_t)f2bf(v.z) | ((uint32_t)(uint16_t)f2bf(v.w) << 16);
  uint2 p; p.x = p0; p.y = p1;
  *(uint2*)(o + i) = p;
}

// convert/transpose all weights: in_proj(bf16), out_proj^T(bf16), post(bf16), pre^T(bf16)
__global__ __launch_bounds__(256) void k_wpack(
    const float* __restrict__ in_proj, const float* __restrict__ out_proj,
    const float* __restrict__ pw0, const float* __restrict__ pw1,
    const float* __restrict__ pw2, const float* __restrict__ pw3,
    const float* __restrict__ qw0, const float* __restrict__ qw1,
    const float* __restrict__ qw2, const float* __restrict__ qw3,
    short* __restrict__ inp_bf, short* __restrict__ postw_bf,
    short* __restrict__ woutT, short* __restrict__ wpreT)
{
  int i = blockIdx.x*256 + threadIdx.x;           // 0 .. 2621439
  if (i < 262144){ inp_bf[i] = f2bf(in_proj[i]); return; }
  i -= 262144;
  if (i < 262144){                                 // out_proj transpose
    int j = i >> 9, t = i & 511;
    woutT[t*512 + j] = f2bf(out_proj[i]);
    return;
  }
  i -= 262144;
  if (i < 1048576){                                // post weights plain convert
    const float* p = (i < 524288) ? ((i < 262144) ? pw0 : pw1)
                                  : ((i < 786432) ? pw2 : pw3);
    postw_bf[i] = f2bf(p[i & 262143]);
    return;
  }
  i -= 1048576;
  {                                                // pre weights transpose
    int g = i >> 18; int r = i & 262143;
    const float* p = (g==0)?qw0:(g==1)?qw1:(g==2)?qw2:qw3;
    int j = r & 511, t = r >> 9;
    wpreT[g*262144 + j*512 + t] = f2bf(p[r]);
  }
}

// b_xz[g][i] = sum_t in_proj[i][t] * pre_b_g[t]
__global__ __launch_bounds__(256) void k_bxz(const float* __restrict__ in_proj,
    const float* __restrict__ b0, const float* __restrict__ b1,
    const float* __restrict__ b2, const float* __restrict__ b3,
    float* __restrict__ bxz)
{
  int idx = blockIdx.x*256 + threadIdx.x;   // 0..2047
  int g = idx >> 9, i = idx & 511;
  const float* bb = (g==0)?b0:(g==1)?b1:(g==2)?b2:b3;
  float s = 0.f;
  for (int t=0;t<512;t++) s += in_proj[i*512+t]*bb[t];
  bxz[idx] = s;
}

// ---------- naive MFMA core for the tiny weight-fuse GEMMs ----------
__device__ __forceinline__ void mfma_2x4_k(const short* a0, const short* a1,
    const short* b0, const short* b1, const short* b2, const short* b3,
    int K, f32x4 acc[2][4])
{
  for (int k0 = 0; k0 < K; k0 += 32){
    bf16x8 av0 = *(const bf16x8*)(a0 + k0);
    bf16x8 av1 = *(const bf16x8*)(a1 + k0);
    bf16x8 bv0 = *(const bf16x8*)(b0 + k0);
    bf16x8 bv1 = *(const bf16x8*)(b1 + k0);
    bf16x8 bv2 = *(const bf16x8*)(b2 + k0);
    bf16x8 bv3 = *(const bf16x8*)(b3 + k0);
    acc[0][0] = __builtin_amdgcn_mfma_f32_16x16x32_bf16(av0, bv0, acc[0][0],0,0,0);
    acc[0][1] = __builtin_amdgcn_mfma_f32_16x16x32_bf16(av0, bv1, acc[0][1],0,0,0);
    acc[0][2] = __builtin_amdgcn_mfma_f32_16x16x32_bf16(av0, bv2, acc[0][2],0,0,0);
    acc[0][3] = __builtin_amdgcn_mfma_f32_16x16x32_bf16(av0, bv3, acc[0][3],0,0,0);
    acc[1][0] = __builtin_amdgcn_mfma_f32_16x16x32_bf16(av1, bv0, acc[1][0],0,0,0);
    acc[1][1] = __builtin_amdgcn_mfma_f32_16x16x32_bf16(av1, bv1, acc[1][1],0,0,0);
    acc[1][2] = __builtin_amdgcn_mfma_f32_16x16x32_bf16(av1, bv2, acc[1][2],0,0,0);
    acc[1][3] = __builtin_amdgcn_mfma_f32_16x16x32_bf16(av1, bv3, acc[1][3],0,0,0);
  }
}

// ---------- W_xz[g] = in_proj @ pre_w_g   (512x512, K=512) ----------
__global__ __launch_bounds__(256) void k_wfuseW(const short* __restrict__ inp_bf,
    const short* __restrict__ wpreT, short* __restrict__ wxz)
{
  int g = blockIdx.z;
  int bn = blockIdx.x * 64, bm = blockIdx.y * 128;
  int lane = threadIdx.x & 63, wave = threadIdx.x >> 6;
  int mr = lane & 15, qk = (lane >> 4) * 8, quad = lane >> 4;
  const short* Bg = wpreT + g*262144;
  const short* a0 = inp_bf + (bm + wave*32 + mr)*512 + qk;
  const short* a1 = a0 + 16*512;
  const short* b0 = Bg + (bn +  0 + mr)*512 + qk;
  const short* b1 = Bg + (bn + 16 + mr)*512 + qk;
  const short* b2 = Bg + (bn + 32 + mr)*512 + qk;
  const short* b3 = Bg + (bn + 48 + mr)*512 + qk;
  f32x4 acc[2][4] = {};
  mfma_2x4_k(a0, a1, b0, b1, b2, b3, 512, acc);
  short* Cg = wxz + g*262144;
  #pragma unroll
  for (int s=0;s<2;s++)
    #pragma unroll
    for (int t=0;t<4;t++)
      #pragma unroll
      for (int r=0;r<4;r++){
        int row = bm + wave*32 + s*16 + quad*4 + r;
        int col = bn + t*16 + mr;
        Cg[row*512 + col] = f2bf(acc[s][t][r]);
      }
}

// ---------- Wog[g] = gain_g * (post_w_g @ out_proj_w), packed [n][g*512+t] ----------
__global__ __launch_bounds__(256) void k_wfuse2(const short* __restrict__ postw_bf,
    const short* __restrict__ woutT, const float* __restrict__ gains,
    short* __restrict__ wogc)
{
  int g = blockIdx.z;
  int bn = blockIdx.x * 64, bm = blockIdx.y * 128;
  int lane = threadIdx.x & 63, wave = threadIdx.x >> 6;
  int mr = lane & 15, qk = (lane >> 4) * 8, quad = lane >> 4;
  const short* Ag = postw_bf + g*262144;
  const short* a0 = Ag + (bm + wave*32 + mr)*512 + qk;
  const short* a1 = a0 + 16*512;
  const short* b0 = woutT + (bn +  0 + mr)*512 + qk;
  const short* b1 = woutT + (bn + 16 + mr)*512 + qk;
  const short* b2 = woutT + (bn + 32 + mr)*512 + qk;
  const short* b3 = woutT + (bn + 48 + mr)*512 + qk;
  f32x4 acc[2][4] = {};
  mfma_2x4_k(a0, a1, b0, b1, b2, b3, 512, acc);
  float gain = gains[g];
  #pragma unroll
  for (int s=0;s<2;s++)
    #pragma unroll
    for (int t=0;t<4;t++)
      #pragma unroll
      for (int r=0;r<4;r++){
        int row = bm + wave*32 + s*16 + quad*4 + r;
        int col = bn + t*16 + mr;
        wogc[row*2048 + g*512 + col] = f2bf(gain * acc[s][t][r]);
      }
}

// ---------- GEMM1 (LDS-staged, m97 structure): 128x128 tile, BK=32, K=512 ----------
// xz[(g*512+b)*49+l][ch] = tok[b][perm_g(l)][:] @ W_xz[g]^T + b_xz[g]
__global__ __launch_bounds__(256) void k_gemm1(const short* __restrict__ tok,
    const short* __restrict__ wxz, const float* __restrict__ bxz, short* __restrict__ xz)
{
  // LDS layout: [quad][row][8 bf16] -> 16B per (quad,row) entry; conflict-free b128 reads
  __shared__ __align__(16) short As[4096];
  __shared__ __align__(16) short Bs[4096];
  int g = blockIdx.z;
  int bn = blockIdx.x * 128, bm = blockIdx.y * 128;
  int tid = threadIdx.x, lane = tid & 63, wave = tid >> 6;

  const short* aG[2]; const short* bG[2]; int ldsOff[2];
  #pragma unroll
  for (int i = 0; i < 2; i++){
    int c = wave*2 + i;            // chunk 0..7: q = c>>1, rows (c&1)*64 + lane
    int q = c >> 1, r = (c & 1)*64 + lane;
    int grow = bm + r;
    int b = grow / 49, l = grow - b*49;
    int sl = perm_idx(g, l);
    aG[i] = tok + ((size_t)(b*49 + sl))*512 + q*8;
    bG[i] = wxz + (size_t)g*262144 + (size_t)(bn + r)*512 + q*8;
    ldsOff[i] = c*512;             // shorts (1024 B per chunk)
  }

  int mr = lane & 15, quad = lane >> 4;
  int wm = (wave & 1)*64, wn = (wave >> 1)*64;
  f32x4 acc[4][4] = {};

  for (int ks = 0; ks < 16; ks++){
    #pragma unroll
    for (int i = 0; i < 2; i++){
      gl_lds16(aG[i], As + ldsOff[i]);
      gl_lds16(bG[i], Bs + ldsOff[i]);
      aG[i] += 32; bG[i] += 32;
    }
    __syncthreads();
    bf16x8 af[4], bfr[4];
    #pragma unroll
    for (int t = 0; t < 4; t++){
      af[t]  = *(const bf16x8*)(As + (quad*128 + wm + t*16 + mr)*8);
      bfr[t] = *(const bf16x8*)(Bs + (quad*128 + wn + t*16 + mr)*8);
    }
    #pragma unroll
    for (int mt = 0; mt < 4; mt++)
      #pragma unroll
      for (int nt = 0; nt < 4; nt++)
        acc[mt][nt] = __builtin_amdgcn_mfma_f32_16x16x32_bf16(af[mt], bfr[nt], acc[mt][nt],0,0,0);
    __syncthreads();
  }

  #pragma unroll
  for (int mt = 0; mt < 4; mt++)
    #pragma unroll
    for (int rr = 0; rr < 4; rr++){
      int row = bm + wm + mt*16 + quad*4 + rr;
      int b = row / 49, l = row - b*49;
      size_t orow = ((size_t)(g*512 + b)*49 + l)*512;
      #pragma unroll
      for (int nt = 0; nt < 4; nt++){
        int col = bn + wn + nt*16 + mr;
        xz[orow + col] = f2bf(acc[mt][nt][rr] + bxz[g*512 + col]);
      }
    }
}

// ---------- stage B: conv -> SiLU -> x_proj(MFMA) -> LN -> dt -> scan -> ycat2 ----------
// ycat2 layout: [rowg = b*49+l][g*512 + ch]  (K-contiguous for gemmF)
__global__ __launch_bounds__(256) void k_stageB(const short* __restrict__ xz,
    const float* __restrict__ cxw, const float* __restrict__ cxb,
    const float* __restrict__ czw, const float* __restrict__ czb,
    const float* __restrict__ xpw, const float* __restrict__ lnw, const float* __restrict__ lnb,
    const float* __restrict__ dtw, const float* __restrict__ dtb,
    const float* __restrict__ Alog, const float* __restrict__ Dp,
    short* __restrict__ ycat)
{
  // LDS layout (bytes): [0,25088) xconv bf16 rows 0..48 (rows 49..63 read-only pad
  // aliasing xdbl -> feeds only discarded MFMA output rows); [25088,34496) xdbl f32 49x48;
  // [34496,59072) xpw bf16 48x256.
  __shared__ __align__(16) char smem[59072];
  short* xconv_s = (short*)smem;
  float* xdbl    = (float*)(smem + 25088);
  short* xpw_s   = (short*)(smem + 34496);

  int gb = blockIdx.x;
  int g = gb >> 9, b = gb & 511;
  int d  = threadIdx.x;           // 0..255 == channel
  const short* xzb = xz + (size_t)gb * 25088;     // 49*512
  short* yb = ycat + (size_t)(b*49) * 2048 + g*512;

  // x depthwise conv (k=3, SAME) + SiLU -> LDS (bf16)
  {
    float w0 = cxw[d*3], w1 = cxw[d*3+1], w2 = cxw[d*3+2], bb = cxb[d];
    float vm = 0.f, v0 = bf2f(xzb[d]);
    for (int l=0;l<49;l++){
      float vp = (l<48) ? bf2f(xzb[(l+1)*512 + d]) : 0.f;
      float c = w0*vm + w1*v0 + w2*vp + bb;
      xconv_s[l*256 + d] = f2bf(c / (1.f + __expf(-c)));
      vm = v0; v0 = vp;
    }
  }
  // z depthwise conv + SiLU -> straight to ycat2 channels 256..511 of this group slice
  {
    float w0 = czw[d*3], w1 = czw[d*3+1], w2 = czw[d*3+2], bb = czb[d];
    float vm = 0.f, v0 = bf2f(xzb[256 + d]);
    for (int l=0;l<49;l++){
      float vp = (l<48) ? bf2f(xzb[(l+1)*512 + 256 + d]) : 0.f;
      float c = w0*vm + w1*v0 + w2*vp + bb;
      yb[l*2048 + 256 + d] = f2bf(c / (1.f + __expf(-c)));
      vm = v0; v0 = vp;
    }
  }
  // stage x_proj_w into LDS as bf16
  for (int i = d; i < 12288; i += 256) xpw_s[i] = f2bf(xpw[i]);
  __syncthreads();

  // x_dbl[l][e] = sum_d xconv[l][d] * xpw[e][d]  via MFMA (M=64 padded, N=48, K=256)
  {
    int lane = d & 63, wave = d >> 6;
    int mr = lane & 15, qk = (lane >> 4) * 8, quad = lane >> 4;
    const short* ar = xconv_s + (wave*16 + mr)*256 + qk;
    f32x4 accp[3] = {};
    #pragma unroll
    for (int k0 = 0; k0 < 256; k0 += 32){
      bf16x8 a = *(const bf16x8*)(ar + k0);
      #pragma unroll
      for (int t=0;t<3;t++){
        bf16x8 bv = *(const bf16x8*)(xpw_s + (t*16 + mr)*256 + qk + k0);
        accp[t] = __builtin_amdgcn_mfma_f32_16x16x32_bf16(a, bv, accp[t],0,0,0);
      }
    }
    #pragma unroll
    for (int t=0;t<3;t++)
      #pragma unroll
      for (int r=0;r<4;r++){
        int row = wave*16 + quad*4 + r;
        if (row < 49) xdbl[row*48 + t*16 + mr] = accp[t][r];
      }
  }
  __syncthreads();

  // layernorm over E=48, one thread per l
  if (d < 49){
    float m = 0.f;
    for (int e=0;e<48;e++) m += xdbl[d*48+e];
    m *= (1.f/48.f);
    float v = 0.f;
    for (int e=0;e<48;e++){ float t = xdbl[d*48+e]-m; v += t*t; }
    v *= (1.f/48.f);
    float r = rsqrtf(v + 1e-5f);
    for (int e=0;e<48;e++) xdbl[d*48+e] = (xdbl[d*48+e]-m)*r*lnw[e] + lnb[e];
  }
  __syncthreads();

  // selective scan (f32), one thread per channel d
  {
    float A[8], h[8];
    #pragma unroll
    for (int n=0;n<8;n++){ A[n] = -__expf(Alog[d*8+n]); h[n] = 0.f; }
    float Dpar = Dp[d], dtbias = dtb[d];
    float w[32];
    #pragma unroll
    for (int r=0;r<32;r++) w[r] = dtw[d*32+r];
    for (int l=0;l<49;l++){
      const float* xr = xdbl + l*48;
      float dtv = dtbias;
      #pragma unroll
      for (int r=0;r<32;r++) dtv += xr[r]*w[r];
      float delta = (dtv > 20.f) ? dtv : log1pf(__expf(dtv));
      float u = bf2f(xconv_s[l*256 + d]);
      float y = 0.f;
      #pragma unroll
      for (int n=0;n<8;n++){
        float dA = __expf(delta * A[n]);
        h[n] = h[n]*dA + delta * xr[32+n] * u;
        y += h[n] * xr[40+n];
      }
      yb[l*2048 + d] = f2bf(y + Dpar*u);
    }
  }
}

// ---------- final GEMM (LDS-staged): out[row][n] = ycat2[row][:] @ wogc[n][:] + biasc ----------
// M=25088, N=512, K=2048
__global__ __launch_bounds__(256) void k_gemmF(const short* __restrict__ ycat,
    const short* __restrict__ wogc, const float* __restrict__ biasc,
    float* __restrict__ out)
{
  __shared__ __align__(16) short As[4096];
  __shared__ __align__(16) short Bs[4096];
  int bn = blockIdx.x * 128, bm = blockIdx.y * 128;
  int tid = threadIdx.x, lane = tid & 63, wave = tid >> 6;

  const short* aG[2]; const short* bG[2]; int ldsOff[2];
  #pragma unroll
  for (int i = 0; i < 2; i++){
    int c = wave*2 + i;
    int q = c >> 1, r = (c & 1)*64 + lane;
    aG[i] = ycat + (size_t)(bm + r)*2048 + q*8;
    bG[i] = wogc + (size_t)(bn + r)*2048 + q*8;
    ldsOff[i] = c*512;
  }

  int mr = lane & 15, quad = lane >> 4;
  int wm = (wave & 1)*64, wn = (wave >> 1)*64;
  f32x4 acc[4][4] = {};

  for (int ks = 0; ks < 64; ks++){
    #pragma unroll
    for (int i = 0; i < 2; i++){
      gl_lds16(aG[i], As + ldsOff[i]);
      gl_lds16(bG[i], Bs + ldsOff[i]);
      aG[i] += 32; bG[i] += 32;
    }
    __syncthreads();
    bf16x8 af[4], bfr[4];
    #pragma unroll
    for (int t = 0; t < 4; t++){
      af[t]  = *(const bf16x8*)(As + (quad*128 + wm + t*16 + mr)*8);
      bfr[t] = *(const bf16x8*)(Bs + (quad*128 + wn + t*16 + mr)*8);
    }
    #pragma unroll
    for (int mt = 0; mt < 4; mt++)
      #pragma unroll
      for (int nt = 0; nt < 4; nt++)
        acc[mt][nt] = __builtin_amdgcn_mfma_f32_16x16x32_bf16(af[mt], bfr[nt], acc[mt][nt],0,0,0);
    __syncthreads();
  }

  #pragma unroll
  for (int mt = 0; mt < 4; mt++)
    #pragma unroll
    for (int rr = 0; rr < 4; rr++){
      int row = bm + wm + mt*16 + quad*4 + rr;
      float* orow = out + (size_t)row*512;
      #pragma unroll
      for (int nt = 0; nt < 4; nt++){
        int col = bn + wn + nt*16 + mr;
        orow[col] = acc[mt][nt][rr] + biasc[col];
      }
    }
}

// ---------- launch ----------
extern "C" void kernel_launch(void* const* d_in, const int* in_sizes, int n_in,
                              void* d_out, int out_size, void* d_ws, size_t ws_size,
                              hipStream_t stream)
{
  const float* tokens    = (const float*)d_in[0];
  const float* pre_w[4]  = {(const float*)d_in[1], (const float*)d_in[3], (const float*)d_in[5], (const float*)d_in[7]};
  const float* pre_b[4]  = {(const float*)d_in[2], (const float*)d_in[4], (const float*)d_in[6], (const float*)d_in[8]};
  const float* post_w[4] = {(const float*)d_in[9], (const float*)d_in[11], (const float*)d_in[13], (const float*)d_in[15]};
  const float* post_b[4] = {(const float*)d_in[10], (const float*)d_in[12], (const float*)d_in[14], (const float*)d_in[16]};
  const float* in_proj   = (const float*)d_in[17];
  const float* conv_x_w  = (const float*)d_in[18];
  const float* conv_x_b  = (const float*)d_in[19];
  const float* conv_z_w  = (const float*)d_in[20];
  const float* conv_z_b  = (const float*)d_in[21];
  const float* x_proj_w  = (const float*)d_in[22];
  const float* ln_w      = (const float*)d_in[23];
  const float* ln_b      = (const float*)d_in[24];
  const float* dt_proj_w = (const float*)d_in[25];
  const float* dt_proj_b = (const float*)d_in[26];
  const float* A_log     = (const float*)d_in[27];
  const float* D_param   = (const float*)d_in[28];
  const float* out_proj  = (const float*)d_in[29];
  const float* gate_log  = (const float*)d_in[30];

  char* ws = (char*)d_ws;
  size_t o = 0;
  short* tok_bf   = (short*)(ws + o); o += 25690112;   // 12845056 bf16
  short* wpreT    = (short*)(ws + o); o += 2097152;    // 4x 512x512 bf16 (transposed)
  short* inp_bf   = (short*)(ws + o); o += 524288;
  short* postw_bf = (short*)(ws + o); o += 2097152;
  short* woutT    = (short*)(ws + o); o += 524288;
  short* wogc     = (short*)(ws + o); o += 2097152;    // 512 x 2048 bf16
  short* wxz      = (short*)(ws + o); o += 2097152;    // 4x 512x512 bf16
  float* bxz      = (float*)(ws + o); o += 8192;
  float* gains    = (float*)(ws + o); o += 64;
  float* biasc    = (float*)(ws + o); o += 2048;
  short* xz       = (short*)(ws + o); o += 102760448;  // 2048*49*512 bf16
  short* ycat     = (short*)(ws + o); o += 102760448;  // 25088 x 2048 bf16

  k_gains<<<1, 512, 0, stream>>>(gate_log, post_b[0], post_b[1], post_b[2], post_b[3], gains, biasc);
  k_tok<<<12544, 256, 0, stream>>>(tokens, tok_bf);
  k_wpack<<<10240, 256, 0, stream>>>(in_proj, out_proj,
      post_w[0], post_w[1], post_w[2], post_w[3],
      pre_w[0], pre_w[1], pre_w[2], pre_w[3],
      inp_bf, postw_bf, woutT, wpreT);
  k_bxz<<<8, 256, 0, stream>>>(in_proj, pre_b[0], pre_b[1], pre_b[2], pre_b[3], bxz);
  k_wfuseW<<<dim3(8,4,4), 256, 0, stream>>>(inp_bf, wpreT, wxz);
  k_wfuse2<<<dim3(8,4,4), 256, 0, stream>>>(postw_bf, woutT, gains, wogc);
  k_gemm1<<<dim3(4,196,4), 256, 0, stream>>>(tok_bf, wxz, bxz, xz);
  k_stageB<<<2048, 256, 0, stream>>>(xz, conv_x_w, conv_x_b, conv_z_w, conv_z_b,
      x_proj_w, ln_w, ln_b, dt_proj_w, dt_proj_b, A_log, D_param, ycat);
  k_gemmF<<<dim3(4,196,1), 256, 0, stream>>>(ycat, wogc, biasc, (float*)d_out);
}

// Round 3
// 707.534 us; speedup vs baseline: 1.4683x; 1.0489x over previous
//
#include <hip/hip_runtime.h>
#include <stdint.h>

// ---------- types ----------
typedef __attribute__((ext_vector_type(8))) short bf16x8;   // 8 bf16 in 4 VGPRs
typedef __attribute__((ext_vector_type(4))) float f32x4;

__device__ __forceinline__ float bf2f(short u){
  union { float f; uint32_t i; } v; v.i = ((uint32_t)(uint16_t)u) << 16; return v.f;
}
__device__ __forceinline__ short f2bf(float x){
  union { float f; uint32_t i; } v; v.f = x;
  uint32_t r = v.i + 0x7FFFu + ((v.i >> 16) & 1u);   // RNE
  return (short)(r >> 16);
}

// async global->LDS, 16B per lane; LDS dest = wave-uniform base + lane*16
__device__ __forceinline__ void gl_lds16(const short* g, short* l){
  __builtin_amdgcn_global_load_lds(
      (__attribute__((address_space(1))) void*)(short*)g,
      (__attribute__((address_space(3))) void*)l, 16, 0, 0);
}

// ---------- permutation tables (WIN=7, compile-time) ----------
__device__ const int d_DIAG[49] = {0,1,7,2,8,14,3,9,15,21,4,10,16,22,28,5,11,17,23,29,35,
  6,12,18,24,30,36,42,13,19,25,31,37,43,20,26,32,38,44,27,33,39,45,34,40,46,41,47,48};
__device__ const int d_ANTI[49] = {6,5,13,4,12,20,3,11,19,27,2,10,18,26,34,1,9,17,25,33,41,
  0,8,16,24,32,40,48,7,15,23,31,39,47,14,22,30,38,46,21,29,37,45,28,36,44,35,43,42};

__device__ __forceinline__ int perm_idx(int g, int l){
  if (g == 0) return l;
  if (g == 1) return (l % 7) * 7 + l / 7;  // V_IDX
  if (g == 2) return d_DIAG[l];
  return d_ANTI[l];
}

// ---------- prep: plain f32->bf16 converts (in_proj, post x4, x_proj_w, dt_proj_w) ----------
__global__ __launch_bounds__(256) void k_conv_all(
    const float* __restrict__ in_proj,
    const float* __restrict__ pw0, const float* __restrict__ pw1,
    const float* __restrict__ pw2, const float* __restrict__ pw3,
    const float* __restrict__ xpw, const float* __restrict__ dtw,
    short* __restrict__ inp_bf, short* __restrict__ postw_bf,
    short* __restrict__ xpw_bf, short* __restrict__ dtw_bf)
{
  int q = blockIdx.x*256 + threadIdx.x;   // quad index, total 332800
  const float* src; short* dst; int off;
  if (q < 65536){ src = in_proj; dst = inp_bf; off = q; }
  else if (q < 65536 + 262144){
    int r = q - 65536; int g = r >> 16; int loc = r & 65535;
    src = (g==0)?pw0:(g==1)?pw1:(g==2)?pw2:pw3;
    dst = postw_bf + g*262144; off = loc;
  }
  else if (q < 65536 + 262144 + 3072){ src = xpw; dst = xpw_bf; off = q - (65536+262144); }
  else { src = dtw; dst = dtw_bf; off = q - (65536+262144+3072); }
  float4 v = *(const float4*)(src + off*4);
  uint32_t p0 = (uint32_t)(uint16_t)f2bf(v.x) | ((uint32_t)(uint16_t)f2bf(v.y) << 16);
  uint32_t p1 = (uint32_t)(uint16_t)f2bf(v.z) | ((uint32_t)(uint16_t)f2bf(v.w) << 16);
  uint2 p; p.x = p0; p.y = p1;
  *(uint2*)(dst + off*4) = p;
}

// ---------- prep: LDS-tiled transpose+convert (pre_w x4 -> wpreT, out_proj -> woutT) ----------
__global__ __launch_bounds__(256) void k_transp(
    const float* __restrict__ pw0, const float* __restrict__ pw1,
    const float* __restrict__ pw2, const float* __restrict__ pw3,
    const float* __restrict__ outp,
    short* __restrict__ wpreT, short* __restrict__ woutT)
{
  __shared__ float tile[64][65];
  int which = blockIdx.y;
  const float* src = (which==0)?pw0:(which==1)?pw1:(which==2)?pw2:(which==3)?pw3:outp;
  short* dst = (which < 4) ? (wpreT + which*262144) : woutT;
  int bi = blockIdx.x >> 3, bj = blockIdx.x & 7;
  int r0 = bi*64, c0 = bj*64;
  int t = threadIdx.x;
  int row = t >> 2, cg = t & 3;
  const float4* s4 = (const float4*)(src + (r0+row)*512 + c0 + cg*16);
  #pragma unroll
  for (int i=0;i<4;i++){
    float4 v = s4[i];
    tile[row][cg*16 + i*4 + 0] = v.x;
    tile[row][cg*16 + i*4 + 1] = v.y;
    tile[row][cg*16 + i*4 + 2] = v.z;
    tile[row][cg*16 + i*4 + 3] = v.w;
  }
  __syncthreads();
  int oc = t >> 2;
  short tmp[16];
  #pragma unroll
  for (int i=0;i<16;i++) tmp[i] = f2bf(tile[cg*16 + i][oc]);
  short* dp = dst + (size_t)(c0+oc)*512 + r0 + cg*16;
  *(bf16x8*)(dp)     = *(bf16x8*)tmp;
  *(bf16x8*)(dp + 8) = *((bf16x8*)tmp + 1);
}

__global__ __launch_bounds__(256) void k_tok(const float* __restrict__ t, short* __restrict__ o){
  int i = (blockIdx.x*256 + threadIdx.x) * 4;
  float4 v = *(const float4*)(t + i);
  uint32_t p0 = (uint32_t)(uint16_t)f2bf(v.x) | ((uint32_t)(uint16_t)f2bf(v.y) << 16);
  uint32_t p1 = (uint32_t)(uint16_t)f2bf(v.z) | ((uint32_t)(uint16_t)f2bf(v.w) << 16);
  uint2 p; p.x = p0; p.y = p1;
  *(uint2*)(o + i) = p;
}

// ---------- prep: b_xz (blocks 0-7) + gains/biasc (block 8) ----------
__global__ __launch_bounds__(256) void k_bxz_gains(const float* __restrict__ in_proj,
    const float* __restrict__ b0, const float* __restrict__ b1,
    const float* __restrict__ b2, const float* __restrict__ b3,
    const float* __restrict__ gl,
    const float* __restrict__ pb0, const float* __restrict__ pb1,
    const float* __restrict__ pb2, const float* __restrict__ pb3,
    float* __restrict__ bxz, float* __restrict__ gains, float* __restrict__ biasc)
{
  if (blockIdx.x < 8){
    int idx = blockIdx.x*256 + threadIdx.x;   // 0..2047
    int g = idx >> 9, i = idx & 511;
    const float* bb = (g==0)?b0:(g==1)?b1:(g==2)?b2:b3;
    float s = 0.f;
    for (int t=0;t<512;t++) s += in_proj[i*512+t]*bb[t];
    bxz[idx] = s;
  } else {
    float m = fmaxf(fmaxf(gl[0], gl[1]), fmaxf(gl[2], gl[3]));
    float e0 = expf(gl[0]-m), e1 = expf(gl[1]-m), e2 = expf(gl[2]-m), e3 = expf(gl[3]-m);
    float s = e0+e1+e2+e3;
    float g0 = e0/s, g1 = e1/s, g2 = e2/s, g3 = e3/s;
    int t = threadIdx.x;
    if (t == 0){ gains[0]=g0; gains[1]=g1; gains[2]=g2; gains[3]=g3; }
    biasc[t]     = g0*pb0[t]     + g1*pb1[t]     + g2*pb2[t]     + g3*pb3[t];
    biasc[t+256] = g0*pb0[t+256] + g1*pb1[t+256] + g2*pb2[t+256] + g3*pb3[t+256];
  }
}

// ---------- register-GEMM core for the tiny weight-fuse GEMMs ----------
__device__ __forceinline__ void mfma_2x4_k(const short* a0, const short* a1,
    const short* b0, const short* b1, const short* b2, const short* b3,
    int K, f32x4 acc[2][4])
{
  for (int k0 = 0; k0 < K; k0 += 32){
    bf16x8 av0 = *(const bf16x8*)(a0 + k0);
    bf16x8 av1 = *(const bf16x8*)(a1 + k0);
    bf16x8 bv0 = *(const bf16x8*)(b0 + k0);
    bf16x8 bv1 = *(const bf16x8*)(b1 + k0);
    bf16x8 bv2 = *(const bf16x8*)(b2 + k0);
    bf16x8 bv3 = *(const bf16x8*)(b3 + k0);
    acc[0][0] = __builtin_amdgcn_mfma_f32_16x16x32_bf16(av0, bv0, acc[0][0],0,0,0);
    acc[0][1] = __builtin_amdgcn_mfma_f32_16x16x32_bf16(av0, bv1, acc[0][1],0,0,0);
    acc[0][2] = __builtin_amdgcn_mfma_f32_16x16x32_bf16(av0, bv2, acc[0][2],0,0,0);
    acc[0][3] = __builtin_amdgcn_mfma_f32_16x16x32_bf16(av0, bv3, acc[0][3],0,0,0);
    acc[1][0] = __builtin_amdgcn_mfma_f32_16x16x32_bf16(av1, bv0, acc[1][0],0,0,0);
    acc[1][1] = __builtin_amdgcn_mfma_f32_16x16x32_bf16(av1, bv1, acc[1][1],0,0,0);
    acc[1][2] = __builtin_amdgcn_mfma_f32_16x16x32_bf16(av1, bv2, acc[1][2],0,0,0);
    acc[1][3] = __builtin_amdgcn_mfma_f32_16x16x32_bf16(av1, bv3, acc[1][3],0,0,0);
  }
}

// ---------- merged weight-fuse: z<4 -> W_xz[g]; z>=4 -> Wog[g] ----------
__global__ __launch_bounds__(256) void k_wfuse(const short* __restrict__ inp_bf,
    const short* __restrict__ wpreT, const short* __restrict__ postw_bf,
    const short* __restrict__ woutT, const float* __restrict__ gains,
    short* __restrict__ wxz, short* __restrict__ wogc)
{
  int z = blockIdx.z; int g = z & 3, which = z >> 2;
  int bn = blockIdx.x * 64, bm = blockIdx.y * 128;
  int lane = threadIdx.x & 63, wave = threadIdx.x >> 6;
  int mr = lane & 15, qk = (lane >> 4) * 8, quad = lane >> 4;
  const short* Am = which ? (postw_bf + g*262144) : inp_bf;
  const short* Bm = which ? woutT : (wpreT + g*262144);
  const short* a0 = Am + (bm + wave*32 + mr)*512 + qk;
  const short* a1 = a0 + 16*512;
  const short* b0 = Bm + (bn +  0 + mr)*512 + qk;
  const short* b1 = Bm + (bn + 16 + mr)*512 + qk;
  const short* b2 = Bm + (bn + 32 + mr)*512 + qk;
  const short* b3 = Bm + (bn + 48 + mr)*512 + qk;
  f32x4 acc[2][4] = {};
  mfma_2x4_k(a0, a1, b0, b1, b2, b3, 512, acc);
  float gain = which ? gains[g] : 1.f;
  #pragma unroll
  for (int s=0;s<2;s++)
    #pragma unroll
    for (int t=0;t<4;t++)
      #pragma unroll
      for (int r=0;r<4;r++){
        int row = bm + wave*32 + s*16 + quad*4 + r;
        int col = bn + t*16 + mr;
        if (which) wogc[row*2048 + g*512 + col] = f2bf(gain * acc[s][t][r]);
        else       wxz[g*262144 + row*512 + col] = f2bf(acc[s][t][r]);
      }
}

// ---------- GEMM1 (LDS-staged): 128x128 tile, BK=32, K=512 ----------
// xz[(g*512+b)*49+l][ch] = tok[b][perm_g(l)][:] @ W_xz[g]^T + b_xz[g]
__global__ __launch_bounds__(256) void k_gemm1(const short* __restrict__ tok,
    const short* __restrict__ wxz, const float* __restrict__ bxz, short* __restrict__ xz)
{
  __shared__ __align__(16) short As[4096];
  __shared__ __align__(16) short Bs[4096];
  int g = blockIdx.z;
  int bn = blockIdx.x * 128, bm = blockIdx.y * 128;
  int tid = threadIdx.x, lane = tid & 63, wave = tid >> 6;

  const short* aG[2]; const short* bG[2]; int ldsOff[2];
  #pragma unroll
  for (int i = 0; i < 2; i++){
    int c = wave*2 + i;
    int q = c >> 1, r = (c & 1)*64 + lane;
    int grow = bm + r;
    int b = grow / 49, l = grow - b*49;
    int sl = perm_idx(g, l);
    aG[i] = tok + ((size_t)(b*49 + sl))*512 + q*8;
    bG[i] = wxz + (size_t)g*262144 + (size_t)(bn + r)*512 + q*8;
    ldsOff[i] = c*512;
  }

  int mr = lane & 15, quad = lane >> 4;
  int wm = (wave & 1)*64, wn = (wave >> 1)*64;
  f32x4 acc[4][4] = {};

  for (int ks = 0; ks < 16; ks++){
    #pragma unroll
    for (int i = 0; i < 2; i++){
      gl_lds16(aG[i], As + ldsOff[i]);
      gl_lds16(bG[i], Bs + ldsOff[i]);
      aG[i] += 32; bG[i] += 32;
    }
    __syncthreads();
    bf16x8 af[4], bfr[4];
    #pragma unroll
    for (int t = 0; t < 4; t++){
      af[t]  = *(const bf16x8*)(As + (quad*128 + wm + t*16 + mr)*8);
      bfr[t] = *(const bf16x8*)(Bs + (quad*128 + wn + t*16 + mr)*8);
    }
    #pragma unroll
    for (int mt = 0; mt < 4; mt++)
      #pragma unroll
      for (int nt = 0; nt < 4; nt++)
        acc[mt][nt] = __builtin_amdgcn_mfma_f32_16x16x32_bf16(af[mt], bfr[nt], acc[mt][nt],0,0,0);
    __syncthreads();
  }

  #pragma unroll
  for (int mt = 0; mt < 4; mt++)
    #pragma unroll
    for (int rr = 0; rr < 4; rr++){
      int row = bm + wm + mt*16 + quad*4 + rr;
      int b = row / 49, l = row - b*49;
      size_t orow = ((size_t)(g*512 + b)*49 + l)*512;
      #pragma unroll
      for (int nt = 0; nt < 4; nt++){
        int col = bn + wn + nt*16 + mr;
        xz[orow + col] = f2bf(acc[mt][nt][rr] + bxz[g*512 + col]);
      }
    }
}

// ---------- stage B: conv -> SiLU -> x_proj(MFMA) -> LN -> dt(MFMA) -> scan -> ycat2 ----------
// ycat2 layout: [rowg = b*49+l][g*512 + ch]
__global__ __launch_bounds__(256, 2) void k_stageB(const short* __restrict__ xz,
    const float* __restrict__ cxw, const float* __restrict__ cxb,
    const float* __restrict__ czw, const float* __restrict__ czb,
    const short* __restrict__ xpw_bf, const float* __restrict__ lnw, const float* __restrict__ lnb,
    const short* __restrict__ dtw_bf, const float* __restrict__ dtb,
    const float* __restrict__ Alog, const float* __restrict__ Dp,
    short* __restrict__ ycat)
{
  // LDS layout (bytes):
  //  [0, 25088)      xconv bf16 [49][256]  (MFMA A reads rows 49..63 spill into xdbl -> discarded rows)
  //  [25088, 34496)  xdbl f32 [49][48]     (dt-MFMA A reads rows 49..63 spill into dtln -> discarded rows)
  //  [34496, 59584)  dtln bf16 [49][256]   (softplus'd delta)
  __shared__ __align__(16) char smem[59584];
  short* xconv_s = (short*)smem;
  float* xdbl    = (float*)(smem + 25088);
  short* dtln    = (short*)(smem + 34496);

  int gb = blockIdx.x;
  int g = gb >> 9, b = gb & 511;
  int d  = threadIdx.x;           // 0..255 == channel
  const short* xzb = xz + (size_t)gb * 25088;     // 49*512
  short* yb = ycat + (size_t)(b*49) * 2048 + g*512;

  // ---- phase 1: depthwise convs + SiLU ----
  {
    float w0 = cxw[d*3], w1 = cxw[d*3+1], w2 = cxw[d*3+2], bb = cxb[d];
    float vm = 0.f, v0 = bf2f(xzb[d]);
    for (int l=0;l<49;l++){
      float vp = (l<48) ? bf2f(xzb[(l+1)*512 + d]) : 0.f;
      float c = w0*vm + w1*v0 + w2*vp + bb;
      xconv_s[l*256 + d] = f2bf(c / (1.f + __expf(-c)));
      vm = v0; v0 = vp;
    }
  }
  {
    float w0 = czw[d*3], w1 = czw[d*3+1], w2 = czw[d*3+2], bb = czb[d];
    float vm = 0.f, v0 = bf2f(xzb[256 + d]);
    for (int l=0;l<49;l++){
      float vp = (l<48) ? bf2f(xzb[(l+1)*512 + 256 + d]) : 0.f;
      float c = w0*vm + w1*v0 + w2*vp + bb;
      yb[l*2048 + 256 + d] = f2bf(c / (1.f + __expf(-c)));
      vm = v0; v0 = vp;
    }
  }
  __syncthreads();

  int lane = d & 63, wave = d >> 6;
  int mr = lane & 15, quad = lane >> 4, qk = quad * 8;

  // ---- phase 2: x_dbl = xconv @ xpw^T via MFMA (M=64 pad, N=48, K=256), B from global (L1) ----
  {
    const short* ar = xconv_s + (wave*16 + mr)*256 + qk;
    f32x4 accp[3] = {};
    #pragma unroll
    for (int k0 = 0; k0 < 256; k0 += 32){
      bf16x8 a = *(const bf16x8*)(ar + k0);
      #pragma unroll
      for (int t=0;t<3;t++){
        bf16x8 bv = *(const bf16x8*)(xpw_bf + (t*16 + mr)*256 + qk + k0);
        accp[t] = __builtin_amdgcn_mfma_f32_16x16x32_bf16(a, bv, accp[t],0,0,0);
      }
    }
    #pragma unroll
    for (int t=0;t<3;t++)
      #pragma unroll
      for (int r=0;r<4;r++){
        int row = wave*16 + quad*4 + r;
        if (row < 49) xdbl[row*48 + t*16 + mr] = accp[t][r];
      }
  }
  __syncthreads();

  // ---- phase 3: layernorm over E=48 (f32x4 vectorized), one thread per l ----
  if (d < 49){
    f32x4* xr4 = (f32x4*)(xdbl + d*48);
    f32x4 s = xr4[0];
    #pragma unroll
    for (int i=1;i<12;i++) s += xr4[i];
    float m = (s[0]+s[1]+s[2]+s[3]) * (1.f/48.f);
    f32x4 vs = {};
    #pragma unroll
    for (int i=0;i<12;i++){ f32x4 t = xr4[i] - m; vs += t*t; }
    float v = (vs[0]+vs[1]+vs[2]+vs[3]) * (1.f/48.f);
    float r = rsqrtf(v + 1e-5f);
    const f32x4* g4 = (const f32x4*)lnw;
    const f32x4* b4 = (const f32x4*)lnb;
    #pragma unroll
    for (int i=0;i<12;i++) xr4[i] = (xr4[i] - m) * r * g4[i] + b4[i];
  }
  __syncthreads();

  // ---- phase 4: dt raw = xln[:,0:32] @ dtw^T via MFMA (M=64 pad, N=256, K=32) + softplus ----
  {
    const float* arow = xdbl + (wave*16 + mr)*48;   // rows >=49 read junk -> discarded
    bf16x8 a;
    #pragma unroll
    for (int j=0;j<8;j++) a[j] = f2bf(arow[qk + j]);
    #pragma unroll 4
    for (int nt = 0; nt < 16; nt++){
      int col = nt*16 + mr;
      bf16x8 bv = *(const bf16x8*)(dtw_bf + col*32 + qk);
      f32x4 acc = {};
      acc = __builtin_amdgcn_mfma_f32_16x16x32_bf16(a, bv, acc,0,0,0);
      float dtbv = dtb[col];
      #pragma unroll
      for (int r=0;r<4;r++){
        int row = wave*16 + quad*4 + r;
        if (row < 49){
          float dtv = acc[r] + dtbv;
          float delta = (dtv > 20.f) ? dtv : log1pf(__expf(dtv));
          dtln[row*256 + col] = f2bf(delta);
        }
      }
    }
  }
  __syncthreads();

  // ---- phase 5: selective scan (f32), one thread per channel d ----
  {
    float A[8], h[8];
    #pragma unroll
    for (int n=0;n<8;n++){ A[n] = -__expf(Alog[d*8+n]); h[n] = 0.f; }
    float Dpar = Dp[d];
    for (int l=0;l<49;l++){
      float delta = bf2f(dtln[l*256 + d]);
      float u = bf2f(xconv_s[l*256 + d]);
      const f32x4* bc = (const f32x4*)(xdbl + l*48 + 32);  // broadcast reads
      f32x4 B0 = bc[0], B1 = bc[1], C0 = bc[2], C1 = bc[3];
      float du = delta * u;
      float y = 0.f;
      #pragma unroll
      for (int n=0;n<4;n++){
        h[n] = h[n]*__expf(delta*A[n]) + du*B0[n];
        y += h[n]*C0[n];
      }
      #pragma unroll
      for (int n=0;n<4;n++){
        h[n+4] = h[n+4]*__expf(delta*A[n+4]) + du*B1[n];
        y += h[n+4]*C1[n];
      }
      yb[l*2048 + d] = f2bf(y + Dpar*u);
    }
  }
}

// ---------- final GEMM (LDS-staged): M=25088, N=512, K=2048 ----------
__global__ __launch_bounds__(256) void k_gemmF(const short* __restrict__ ycat,
    const short* __restrict__ wogc, const float* __restrict__ biasc,
    float* __restrict__ out)
{
  __shared__ __align__(16) short As[4096];
  __shared__ __align__(16) short Bs[4096];
  int bn = blockIdx.x * 128, bm = blockIdx.y * 128;
  int tid = threadIdx.x, lane = tid & 63, wave = tid >> 6;

  const short* aG[2]; const short* bG[2]; int ldsOff[2];
  #pragma unroll
  for (int i = 0; i < 2; i++){
    int c = wave*2 + i;
    int q = c >> 1, r = (c & 1)*64 + lane;
    aG[i] = ycat + (size_t)(bm + r)*2048 + q*8;
    bG[i] = wogc + (size_t)(bn + r)*2048 + q*8;
    ldsOff[i] = c*512;
  }

  int mr = lane & 15, quad = lane >> 4;
  int wm = (wave & 1)*64, wn = (wave >> 1)*64;
  f32x4 acc[4][4] = {};

  for (int ks = 0; ks < 64; ks++){
    #pragma unroll
    for (int i = 0; i < 2; i++){
      gl_lds16(aG[i], As + ldsOff[i]);
      gl_lds16(bG[i], Bs + ldsOff[i]);
      aG[i] += 32; bG[i] += 32;
    }
    __syncthreads();
    bf16x8 af[4], bfr[4];
    #pragma unroll
    for (int t = 0; t < 4; t++){
      af[t]  = *(const bf16x8*)(As + (quad*128 + wm + t*16 + mr)*8);
      bfr[t] = *(const bf16x8*)(Bs + (quad*128 + wn + t*16 + mr)*8);
    }
    #pragma unroll
    for (int mt = 0; mt < 4; mt++)
      #pragma unroll
      for (int nt = 0; nt < 4; nt++)
        acc[mt][nt] = __builtin_amdgcn_mfma_f32_16x16x32_bf16(af[mt], bfr[nt], acc[mt][nt],0,0,0);
    __syncthreads();
  }

  #pragma unroll
  for (int mt = 0; mt < 4; mt++)
    #pragma unroll
    for (int rr = 0; rr < 4; rr++){
      int row = bm + wm + mt*16 + quad*4 + rr;
      float* orow = out + (size_t)row*512;
      #pragma unroll
      for (int nt = 0; nt < 4; nt++){
        int col = bn + wn + nt*16 + mr;
        orow[col] = acc[mt][nt][rr] + biasc[col];
      }
    }
}

// ---------- launch ----------
extern "C" void kernel_launch(void* const* d_in, const int* in_sizes, int n_in,
                              void* d_out, int out_size, void* d_ws, size_t ws_size,
                              hipStream_t stream)
{
  const float* tokens    = (const float*)d_in[0];
  const float* pre_w[4]  = {(const float*)d_in[1], (const float*)d_in[3], (const float*)d_in[5], (const float*)d_in[7]};
  const float* pre_b[4]  = {(const float*)d_in[2], (const float*)d_in[4], (const float*)d_in[6], (const float*)d_in[8]};
  const float* post_w[4] = {(const float*)d_in[9], (const float*)d_in[11], (const float*)d_in[13], (const float*)d_in[15]};
  const float* post_b[4] = {(const float*)d_in[10], (const float*)d_in[12], (const float*)d_in[14], (const float*)d_in[16]};
  const float* in_proj   = (const float*)d_in[17];
  const float* conv_x_w  = (const float*)d_in[18];
  const float* conv_x_b  = (const float*)d_in[19];
  const float* conv_z_w  = (const float*)d_in[20];
  const float* conv_z_b  = (const float*)d_in[21];
  const float* x_proj_w  = (const float*)d_in[22];
  const float* ln_w      = (const float*)d_in[23];
  const float* ln_b      = (const float*)d_in[24];
  const float* dt_proj_w = (const float*)d_in[25];
  const float* dt_proj_b = (const float*)d_in[26];
  const float* A_log     = (const float*)d_in[27];
  const float* D_param   = (const float*)d_in[28];
  const float* out_proj  = (const float*)d_in[29];
  const float* gate_log  = (const float*)d_in[30];

  char* ws = (char*)d_ws;
  size_t o = 0;
  short* tok_bf   = (short*)(ws + o); o += 25690112;   // 12845056 bf16
  short* wpreT    = (short*)(ws + o); o += 2097152;    // 4x 512x512 bf16 (transposed)
  short* inp_bf   = (short*)(ws + o); o += 524288;
  short* postw_bf = (short*)(ws + o); o += 2097152;
  short* woutT    = (short*)(ws + o); o += 524288;
  short* wogc     = (short*)(ws + o); o += 2097152;    // 512 x 2048 bf16
  short* wxz      = (short*)(ws + o); o += 2097152;    // 4x 512x512 bf16
  short* xpw_bf   = (short*)(ws + o); o += 24576;      // 48x256 bf16
  short* dtw_bf   = (short*)(ws + o); o += 16384;      // 256x32 bf16
  float* bxz      = (float*)(ws + o); o += 8192;
  float* gains    = (float*)(ws + o); o += 64;
  float* biasc    = (float*)(ws + o); o += 2048;
  short* xz       = (short*)(ws + o); o += 102760448;  // 2048*49*512 bf16
  short* ycat     = (short*)(ws + o); o += 102760448;  // 25088 x 2048 bf16

  k_conv_all<<<1300, 256, 0, stream>>>(in_proj,
      post_w[0], post_w[1], post_w[2], post_w[3],
      x_proj_w, dt_proj_w, inp_bf, postw_bf, xpw_bf, dtw_bf);
  k_transp<<<dim3(64,5), 256, 0, stream>>>(pre_w[0], pre_w[1], pre_w[2], pre_w[3],
      out_proj, wpreT, woutT);
  k_tok<<<12544, 256, 0, stream>>>(tokens, tok_bf);
  k_bxz_gains<<<9, 256, 0, stream>>>(in_proj, pre_b[0], pre_b[1], pre_b[2], pre_b[3],
      gate_log, post_b[0], post_b[1], post_b[2], post_b[3], bxz, gains, biasc);
  k_wfuse<<<dim3(8,4,8), 256, 0, stream>>>(inp_bf, wpreT, postw_bf, woutT, gains, wxz, wogc);
  k_gemm1<<<dim3(4,196,4), 256, 0, stream>>>(tok_bf, wxz, bxz, xz);
  k_stageB<<<2048, 256, 0, stream>>>(xz, conv_x_w, conv_x_b, conv_z_w, conv_z_b,
      xpw_bf, ln_w, ln_b, dtw_bf, dt_proj_b, A_log, D_param, ycat);
  k_gemmF<<<dim3(4,196,1), 256, 0, stream>>>(ycat, wogc, biasc, (float*)d_out);
}

// Round 4
// 687.109 us; speedup vs baseline: 1.5120x; 1.0297x over previous
//
#include <hip/hip_runtime.h>
#include <stdint.h>

// ---------- types ----------
typedef __attribute__((ext_vector_type(8))) short bf16x8;   // 8 bf16 in 4 VGPRs
typedef __attribute__((ext_vector_type(4))) float f32x4;

__device__ __forceinline__ float bf2f(short u){
  union { float f; uint32_t i; } v; v.i = ((uint32_t)(uint16_t)u) << 16; return v.f;
}
__device__ __forceinline__ short f2bf(float x){
  union { float f; uint32_t i; } v; v.f = x;
  uint32_t r = v.i + 0x7FFFu + ((v.i >> 16) & 1u);   // RNE
  return (short)(r >> 16);
}

// async global->LDS, 16B per lane; LDS dest = wave-uniform base + lane*16
__device__ __forceinline__ void gl_lds16(const short* g, short* l){
  __builtin_amdgcn_global_load_lds(
      (__attribute__((address_space(1))) void*)(short*)g,
      (__attribute__((address_space(3))) void*)l, 16, 0, 0);
}

// ---------- permutation tables (WIN=7, compile-time) ----------
__device__ const int d_DIAG[49] = {0,1,7,2,8,14,3,9,15,21,4,10,16,22,28,5,11,17,23,29,35,
  6,12,18,24,30,36,42,13,19,25,31,37,43,20,26,32,38,44,27,33,39,45,34,40,46,41,47,48};
__device__ const int d_ANTI[49] = {6,5,13,4,12,20,3,11,19,27,2,10,18,26,34,1,9,17,25,33,41,
  0,8,16,24,32,40,48,7,15,23,31,39,47,14,22,30,38,46,21,29,37,45,28,36,44,35,43,42};

__device__ __forceinline__ int perm_idx(int g, int l){
  if (g == 0) return l;
  if (g == 1) return (l % 7) * 7 + l / 7;  // V_IDX
  if (g == 2) return d_DIAG[l];
  return d_ANTI[l];
}

// ---------- prep: plain f32->bf16 converts (in_proj, post x4, x_proj_w, dt_proj_w) ----------
__global__ __launch_bounds__(256) void k_conv_all(
    const float* __restrict__ in_proj,
    const float* __restrict__ pw0, const float* __restrict__ pw1,
    const float* __restrict__ pw2, const float* __restrict__ pw3,
    const float* __restrict__ xpw, const float* __restrict__ dtw,
    short* __restrict__ inp_bf, short* __restrict__ postw_bf,
    short* __restrict__ xpw_bf, short* __restrict__ dtw_bf)
{
  int q = blockIdx.x*256 + threadIdx.x;   // quad index, total 332800
  const float* src; short* dst; int off;
  if (q < 65536){ src = in_proj; dst = inp_bf; off = q; }
  else if (q < 65536 + 262144){
    int r = q - 65536; int g = r >> 16; int loc = r & 65535;
    src = (g==0)?pw0:(g==1)?pw1:(g==2)?pw2:pw3;
    dst = postw_bf + g*262144; off = loc;
  }
  else if (q < 65536 + 262144 + 3072){ src = xpw; dst = xpw_bf; off = q - (65536+262144); }
  else { src = dtw; dst = dtw_bf; off = q - (65536+262144+3072); }
  float4 v = *(const float4*)(src + off*4);
  uint32_t p0 = (uint32_t)(uint16_t)f2bf(v.x) | ((uint32_t)(uint16_t)f2bf(v.y) << 16);
  uint32_t p1 = (uint32_t)(uint16_t)f2bf(v.z) | ((uint32_t)(uint16_t)f2bf(v.w) << 16);
  uint2 p; p.x = p0; p.y = p1;
  *(uint2*)(dst + off*4) = p;
}

// ---------- prep: LDS-tiled transpose+convert (pre_w x4 -> wpreT, out_proj -> woutT) ----------
__global__ __launch_bounds__(256) void k_transp(
    const float* __restrict__ pw0, const float* __restrict__ pw1,
    const float* __restrict__ pw2, const float* __restrict__ pw3,
    const float* __restrict__ outp,
    short* __restrict__ wpreT, short* __restrict__ woutT)
{
  __shared__ float tile[64][65];
  int which = blockIdx.y;
  const float* src = (which==0)?pw0:(which==1)?pw1:(which==2)?pw2:(which==3)?pw3:outp;
  short* dst = (which < 4) ? (wpreT + which*262144) : woutT;
  int bi = blockIdx.x >> 3, bj = blockIdx.x & 7;
  int r0 = bi*64, c0 = bj*64;
  int t = threadIdx.x;
  int row = t >> 2, cg = t & 3;
  const float4* s4 = (const float4*)(src + (r0+row)*512 + c0 + cg*16);
  #pragma unroll
  for (int i=0;i<4;i++){
    float4 v = s4[i];
    tile[row][cg*16 + i*4 + 0] = v.x;
    tile[row][cg*16 + i*4 + 1] = v.y;
    tile[row][cg*16 + i*4 + 2] = v.z;
    tile[row][cg*16 + i*4 + 3] = v.w;
  }
  __syncthreads();
  int oc = t >> 2;
  short tmp[16];
  #pragma unroll
  for (int i=0;i<16;i++) tmp[i] = f2bf(tile[cg*16 + i][oc]);
  short* dp = dst + (size_t)(c0+oc)*512 + r0 + cg*16;
  *(bf16x8*)(dp)     = *(bf16x8*)tmp;
  *(bf16x8*)(dp + 8) = *((bf16x8*)tmp + 1);
}

__global__ __launch_bounds__(256) void k_tok(const float* __restrict__ t, short* __restrict__ o){
  int i = (blockIdx.x*256 + threadIdx.x) * 4;
  float4 v = *(const float4*)(t + i);
  uint32_t p0 = (uint32_t)(uint16_t)f2bf(v.x) | ((uint32_t)(uint16_t)f2bf(v.y) << 16);
  uint32_t p1 = (uint32_t)(uint16_t)f2bf(v.z) | ((uint32_t)(uint16_t)f2bf(v.w) << 16);
  uint2 p; p.x = p0; p.y = p1;
  *(uint2*)(o + i) = p;
}

// ---------- prep: b_xz (blocks 0-7) + gains/biasc (block 8) ----------
__global__ __launch_bounds__(256) void k_bxz_gains(const float* __restrict__ in_proj,
    const float* __restrict__ b0, const float* __restrict__ b1,
    const float* __restrict__ b2, const float* __restrict__ b3,
    const float* __restrict__ gl,
    const float* __restrict__ pb0, const float* __restrict__ pb1,
    const float* __restrict__ pb2, const float* __restrict__ pb3,
    float* __restrict__ bxz, float* __restrict__ gains, float* __restrict__ biasc)
{
  if (blockIdx.x < 8){
    int idx = blockIdx.x*256 + threadIdx.x;   // 0..2047
    int g = idx >> 9, i = idx & 511;
    const float* bb = (g==0)?b0:(g==1)?b1:(g==2)?b2:b3;
    float s = 0.f;
    for (int t=0;t<512;t++) s += in_proj[i*512+t]*bb[t];
    bxz[idx] = s;
  } else {
    float m = fmaxf(fmaxf(gl[0], gl[1]), fmaxf(gl[2], gl[3]));
    float e0 = expf(gl[0]-m), e1 = expf(gl[1]-m), e2 = expf(gl[2]-m), e3 = expf(gl[3]-m);
    float s = e0+e1+e2+e3;
    float g0 = e0/s, g1 = e1/s, g2 = e2/s, g3 = e3/s;
    int t = threadIdx.x;
    if (t == 0){ gains[0]=g0; gains[1]=g1; gains[2]=g2; gains[3]=g3; }
    biasc[t]     = g0*pb0[t]     + g1*pb1[t]     + g2*pb2[t]     + g3*pb3[t];
    biasc[t+256] = g0*pb0[t+256] + g1*pb1[t+256] + g2*pb2[t+256] + g3*pb3[t+256];
  }
}

// ---------- register-GEMM core for the tiny weight-fuse GEMMs ----------
__device__ __forceinline__ void mfma_2x4_k(const short* a0, const short* a1,
    const short* b0, const short* b1, const short* b2, const short* b3,
    int K, f32x4 acc[2][4])
{
  for (int k0 = 0; k0 < K; k0 += 32){
    bf16x8 av0 = *(const bf16x8*)(a0 + k0);
    bf16x8 av1 = *(const bf16x8*)(a1 + k0);
    bf16x8 bv0 = *(const bf16x8*)(b0 + k0);
    bf16x8 bv1 = *(const bf16x8*)(b1 + k0);
    bf16x8 bv2 = *(const bf16x8*)(b2 + k0);
    bf16x8 bv3 = *(const bf16x8*)(b3 + k0);
    acc[0][0] = __builtin_amdgcn_mfma_f32_16x16x32_bf16(av0, bv0, acc[0][0],0,0,0);
    acc[0][1] = __builtin_amdgcn_mfma_f32_16x16x32_bf16(av0, bv1, acc[0][1],0,0,0);
    acc[0][2] = __builtin_amdgcn_mfma_f32_16x16x32_bf16(av0, bv2, acc[0][2],0,0,0);
    acc[0][3] = __builtin_amdgcn_mfma_f32_16x16x32_bf16(av0, bv3, acc[0][3],0,0,0);
    acc[1][0] = __builtin_amdgcn_mfma_f32_16x16x32_bf16(av1, bv0, acc[1][0],0,0,0);
    acc[1][1] = __builtin_amdgcn_mfma_f32_16x16x32_bf16(av1, bv1, acc[1][1],0,0,0);
    acc[1][2] = __builtin_amdgcn_mfma_f32_16x16x32_bf16(av1, bv2, acc[1][2],0,0,0);
    acc[1][3] = __builtin_amdgcn_mfma_f32_16x16x32_bf16(av1, bv3, acc[1][3],0,0,0);
  }
}

// ---------- merged weight-fuse: z<4 -> W_xz[g]; z>=4 -> Wog[g] ----------
__global__ __launch_bounds__(256) void k_wfuse(const short* __restrict__ inp_bf,
    const short* __restrict__ wpreT, const short* __restrict__ postw_bf,
    const short* __restrict__ woutT, const float* __restrict__ gains,
    short* __restrict__ wxz, short* __restrict__ wogc)
{
  int z = blockIdx.z; int g = z & 3, which = z >> 2;
  int bn = blockIdx.x * 64, bm = blockIdx.y * 128;
  int lane = threadIdx.x & 63, wave = threadIdx.x >> 6;
  int mr = lane & 15, qk = (lane >> 4) * 8, quad = lane >> 4;
  const short* Am = which ? (postw_bf + g*262144) : inp_bf;
  const short* Bm = which ? woutT : (wpreT + g*262144);
  const short* a0 = Am + (bm + wave*32 + mr)*512 + qk;
  const short* a1 = a0 + 16*512;
  const short* b0 = Bm + (bn +  0 + mr)*512 + qk;
  const short* b1 = Bm + (bn + 16 + mr)*512 + qk;
  const short* b2 = Bm + (bn + 32 + mr)*512 + qk;
  const short* b3 = Bm + (bn + 48 + mr)*512 + qk;
  f32x4 acc[2][4] = {};
  mfma_2x4_k(a0, a1, b0, b1, b2, b3, 512, acc);
  float gain = which ? gains[g] : 1.f;
  #pragma unroll
  for (int s=0;s<2;s++)
    #pragma unroll
    for (int t=0;t<4;t++)
      #pragma unroll
      for (int r=0;r<4;r++){
        int row = bm + wave*32 + s*16 + quad*4 + r;
        int col = bn + t*16 + mr;
        if (which) wogc[row*2048 + g*512 + col] = f2bf(gain * acc[s][t][r]);
        else       wxz[g*262144 + row*512 + col] = f2bf(acc[s][t][r]);
      }
}

// ---------- GEMM1 (LDS-staged): 128x128 tile, BK=32, K=512 ----------
// xz[(g*512+b)*49+l][ch] = tok[b][perm_g(l)][:] @ W_xz[g]^T + b_xz[g]
__global__ __launch_bounds__(256) void k_gemm1(const short* __restrict__ tok,
    const short* __restrict__ wxz, const float* __restrict__ bxz, short* __restrict__ xz)
{
  __shared__ __align__(16) short As[4096];
  __shared__ __align__(16) short Bs[4096];
  int g = blockIdx.z;
  int bn = blockIdx.x * 128, bm = blockIdx.y * 128;
  int tid = threadIdx.x, lane = tid & 63, wave = tid >> 6;

  const short* aG[2]; const short* bG[2]; int ldsOff[2];
  #pragma unroll
  for (int i = 0; i < 2; i++){
    int c = wave*2 + i;
    int q = c >> 1, r = (c & 1)*64 + lane;
    int grow = bm + r;
    int b = grow / 49, l = grow - b*49;
    int sl = perm_idx(g, l);
    aG[i] = tok + ((size_t)(b*49 + sl))*512 + q*8;
    bG[i] = wxz + (size_t)g*262144 + (size_t)(bn + r)*512 + q*8;
    ldsOff[i] = c*512;
  }

  int mr = lane & 15, quad = lane >> 4;
  int wm = (wave & 1)*64, wn = (wave >> 1)*64;
  f32x4 acc[4][4] = {};

  for (int ks = 0; ks < 16; ks++){
    #pragma unroll
    for (int i = 0; i < 2; i++){
      gl_lds16(aG[i], As + ldsOff[i]);
      gl_lds16(bG[i], Bs + ldsOff[i]);
      aG[i] += 32; bG[i] += 32;
    }
    __syncthreads();
    bf16x8 af[4], bfr[4];
    #pragma unroll
    for (int t = 0; t < 4; t++){
      af[t]  = *(const bf16x8*)(As + (quad*128 + wm + t*16 + mr)*8);
      bfr[t] = *(const bf16x8*)(Bs + (quad*128 + wn + t*16 + mr)*8);
    }
    #pragma unroll
    for (int mt = 0; mt < 4; mt++)
      #pragma unroll
      for (int nt = 0; nt < 4; nt++)
        acc[mt][nt] = __builtin_amdgcn_mfma_f32_16x16x32_bf16(af[mt], bfr[nt], acc[mt][nt],0,0,0);
    __syncthreads();
  }

  #pragma unroll
  for (int mt = 0; mt < 4; mt++)
    #pragma unroll
    for (int rr = 0; rr < 4; rr++){
      int row = bm + wm + mt*16 + quad*4 + rr;
      int b = row / 49, l = row - b*49;
      size_t orow = ((size_t)(g*512 + b)*49 + l)*512;
      #pragma unroll
      for (int nt = 0; nt < 4; nt++){
        int col = bn + wn + nt*16 + mr;
        xz[orow + col] = f2bf(acc[mt][nt][rr] + bxz[g*512 + col]);
      }
    }
}

// ---------- NEW k_conv: depthwise conv3 + SiLU, fully parallel ----------
// x-silu -> ycat[row][g*512 + ch]  (u slot; scan overwrites with y in place)
// z-silu -> ycat[row][g*512 + 256 + ch]
__global__ __launch_bounds__(256) void k_conv(const short* __restrict__ xz,
    const float* __restrict__ cxw, const float* __restrict__ cxb,
    const float* __restrict__ czw, const float* __restrict__ czb,
    short* __restrict__ ycat)
{
  int t = threadIdx.x;
  int oct = t & 63, lstart = t >> 6;
  int ch0 = oct * 8;
  bool isx = ch0 < 256;
  int cc0 = isx ? ch0 : ch0 - 256;
  const float* wsrc = isx ? cxw : czw;
  const float* bsrc = isx ? cxb : czb;
  float w0[8], w1[8], w2[8], bb[8];
  #pragma unroll
  for (int e=0;e<8;e++){
    w0[e] = wsrc[(cc0+e)*3]; w1[e] = wsrc[(cc0+e)*3+1]; w2[e] = wsrc[(cc0+e)*3+2];
    bb[e] = bsrc[cc0+e];
  }
  int gb = blockIdx.x; int g = gb >> 9, b = gb & 511;
  const short* src = xz + (size_t)gb*25088 + ch0;
  short* dst = ycat + (size_t)(b*49)*2048 + g*512 + ch0;
  for (int l = lstart; l < 49; l += 4){
    bf16x8 vm = {}, vp = {};
    bf16x8 v0 = *(const bf16x8*)(src + l*512);
    if (l > 0)  vm = *(const bf16x8*)(src + (l-1)*512);
    if (l < 48) vp = *(const bf16x8*)(src + (l+1)*512);
    short ov[8];
    #pragma unroll
    for (int e=0;e<8;e++){
      float x = w0[e]*bf2f(vm[e]) + w1[e]*bf2f(v0[e]) + w2[e]*bf2f(vp[e]) + bb[e];
      ov[e] = f2bf(x / (1.f + __expf(-x)));
    }
    *(bf16x8*)(dst + l*2048) = *(bf16x8*)ov;
  }
}

// ---------- NEW k_xproj: x_proj GEMM + LN + dt GEMM + softplus ----------
// M=100352 flat rows (784 blocks x 128 rows), A = u from ycat, K=256.
// Writes dtln[grow*256+col] (bf16 delta) and bc[grow*16+j] (f32, LN'd B|C).
__global__ __launch_bounds__(256) void k_xproj(const short* __restrict__ ycat,
    const short* __restrict__ xpw_bf, const float* __restrict__ lnw, const float* __restrict__ lnb,
    const short* __restrict__ dtw_bf, const float* __restrict__ dtb,
    short* __restrict__ dtln, float* __restrict__ bc)
{
  // LDS: xd f32 [128][52] = 26624 B ; xln_bf bf16 [128][40] = 10240 B
  __shared__ __align__(16) char smem[36864];
  float* xd = (float*)smem;
  short* xln = (short*)(smem + 26624);

  int bm = blockIdx.x * 128;
  int g = bm / 25088;                   // uniform per block (128 | 25088)
  int tid = threadIdx.x, lane = tid & 63, w = tid >> 6;
  int mr = lane & 15, quad = lane >> 4, qk = quad * 8;

  // ---- phase 1: x_dbl = u @ xpw^T  (tile 128x48, K=256) ----
  {
    const short* ap[2];
    #pragma unroll
    for (int s=0;s<2;s++)
      ap[s] = ycat + (size_t)(bm - g*25088 + w*32 + s*16 + mr)*2048 + g*512 + qk;
    f32x4 acc[2][3] = {};
    #pragma unroll
    for (int k0 = 0; k0 < 256; k0 += 32){
      bf16x8 av[2];
      #pragma unroll
      for (int s=0;s<2;s++) av[s] = *(const bf16x8*)(ap[s] + k0);
      #pragma unroll
      for (int t=0;t<3;t++){
        bf16x8 bv = *(const bf16x8*)(xpw_bf + (t*16 + mr)*256 + qk + k0);
        #pragma unroll
        for (int s=0;s<2;s++)
          acc[s][t] = __builtin_amdgcn_mfma_f32_16x16x32_bf16(av[s], bv, acc[s][t],0,0,0);
      }
    }
    #pragma unroll
    for (int s=0;s<2;s++)
      #pragma unroll
      for (int t=0;t<3;t++)
        #pragma unroll
        for (int r=0;r<4;r++)
          xd[(w*32 + s*16 + quad*4 + r)*52 + t*16 + mr] = acc[s][t][r];
  }
  __syncthreads();

  // ---- phase 2: LN per row (threads 0..127), write dt-cols to xln (bf16) + B/C to global ----
  if (tid < 128){
    f32x4* xr4 = (f32x4*)(xd + tid*52);
    f32x4 s = xr4[0];
    #pragma unroll
    for (int i=1;i<12;i++) s += xr4[i];
    float m = (s[0]+s[1]+s[2]+s[3]) * (1.f/48.f);
    f32x4 vs = {};
    #pragma unroll
    for (int i=0;i<12;i++){ f32x4 d = xr4[i] - m; vs += d*d; }
    float var = (vs[0]+vs[1]+vs[2]+vs[3]) * (1.f/48.f);
    float rstd = rsqrtf(var + 1e-5f);
    const f32x4* g4 = (const f32x4*)lnw;
    const f32x4* b4 = (const f32x4*)lnb;
    uint32_t* xlr = (uint32_t*)(xln + tid*40);
    #pragma unroll
    for (int i=0;i<8;i++){       // cols 0..31 -> xln bf16
      f32x4 v = (xr4[i] - m) * rstd * g4[i] + b4[i];
      xlr[2*i]   = (uint32_t)(uint16_t)f2bf(v[0]) | ((uint32_t)(uint16_t)f2bf(v[1]) << 16);
      xlr[2*i+1] = (uint32_t)(uint16_t)f2bf(v[2]) | ((uint32_t)(uint16_t)f2bf(v[3]) << 16);
    }
    f32x4* bco = (f32x4*)(bc + (size_t)(bm + tid)*16);
    #pragma unroll
    for (int i=8;i<12;i++)       // cols 32..47 -> bc f32
      bco[i-8] = (xr4[i] - m) * rstd * g4[i] + b4[i];
  }
  __syncthreads();

  // ---- phase 3: dt = xln[:,0:32] @ dtw^T (K=32, N=256) + bias + softplus -> dtln ----
  {
    bf16x8 a[2];
    #pragma unroll
    for (int s=0;s<2;s++)
      a[s] = *(const bf16x8*)(xln + (w*32 + s*16 + mr)*40 + qk);
    #pragma unroll 4
    for (int nt=0; nt<16; nt++){
      int col = nt*16 + mr;
      bf16x8 bv = *(const bf16x8*)(dtw_bf + col*32 + qk);
      float dtbv = dtb[col];
      #pragma unroll
      for (int s=0;s<2;s++){
        f32x4 acc = {};
        acc = __builtin_amdgcn_mfma_f32_16x16x32_bf16(a[s], bv, acc,0,0,0);
        #pragma unroll
        for (int r=0;r<4;r++){
          int grow = bm + w*32 + s*16 + quad*4 + r;
          float dtv = acc[r] + dtbv;
          float delta = (dtv > 20.f) ? dtv : log1pf(__expf(dtv));
          dtln[(size_t)grow*256 + col] = f2bf(delta);
        }
      }
    }
  }
}

// ---------- NEW k_scan: selective scan, one block per gb, u->y in place ----------
__global__ __launch_bounds__(256) void k_scan(short* __restrict__ ycat,
    const short* __restrict__ dtln, const float* __restrict__ bc,
    const float* __restrict__ Alog, const float* __restrict__ Dp)
{
  __shared__ __align__(16) float bcs[784];   // [49][16]
  int gb = blockIdx.x; int g = gb >> 9, b = gb & 511;
  int d = threadIdx.x;
  if (d < 196) ((f32x4*)bcs)[d] = ((const f32x4*)(bc + (size_t)gb*784))[d];
  __syncthreads();

  float A[8], h[8];
  {
    f32x4 a0 = *(const f32x4*)(Alog + d*8);
    f32x4 a1 = *(const f32x4*)(Alog + d*8 + 4);
    #pragma unroll
    for (int n=0;n<4;n++){ A[n] = -__expf(a0[n]); A[n+4] = -__expf(a1[n]); h[n]=0.f; h[n+4]=0.f; }
  }
  float Dpar = Dp[d];

  const short* dptr = dtln + (size_t)gb*49*256 + d;
  short* uptr = ycat + (size_t)(b*49)*2048 + g*512 + d;

  float dn = bf2f(dptr[0]);
  float un = bf2f(uptr[0]);
  for (int l=0;l<49;l++){
    float delta = dn, u = un;
    if (l < 48){ dn = bf2f(dptr[(l+1)*256]); un = bf2f(uptr[(l+1)*2048]); }
    const f32x4* bcr = (const f32x4*)(bcs + l*16);
    f32x4 B0 = bcr[0], B1 = bcr[1], C0 = bcr[2], C1 = bcr[3];
    float du = delta * u;
    float y = 0.f;
    #pragma unroll
    for (int n=0;n<4;n++){
      h[n] = h[n]*__expf(delta*A[n]) + du*B0[n];
      y += h[n]*C0[n];
    }
    #pragma unroll
    for (int n=0;n<4;n++){
      h[n+4] = h[n+4]*__expf(delta*A[n+4]) + du*B1[n];
      y += h[n+4]*C1[n];
    }
    uptr[l*2048] = f2bf(y + Dpar*u);
  }
}

// ---------- final GEMM (LDS-staged): M=25088, N=512, K=2048 ----------
__global__ __launch_bounds__(256) void k_gemmF(const short* __restrict__ ycat,
    const short* __restrict__ wogc, const float* __restrict__ biasc,
    float* __restrict__ out)
{
  __shared__ __align__(16) short As[4096];
  __shared__ __align__(16) short Bs[4096];
  int bn = blockIdx.x * 128, bm = blockIdx.y * 128;
  int tid = threadIdx.x, lane = tid & 63, wave = tid >> 6;

  const short* aG[2]; const short* bG[2]; int ldsOff[2];
  #pragma unroll
  for (int i = 0; i < 2; i++){
    int c = wave*2 + i;
    int q = c >> 1, r = (c & 1)*64 + lane;
    aG[i] = ycat + (size_t)(bm + r)*2048 + q*8;
    bG[i] = wogc + (size_t)(bn + r)*2048 + q*8;
    ldsOff[i] = c*512;
  }

  int mr = lane & 15, quad = lane >> 4;
  int wm = (wave & 1)*64, wn = (wave >> 1)*64;
  f32x4 acc[4][4] = {};

  for (int ks = 0; ks < 64; ks++){
    #pragma unroll
    for (int i = 0; i < 2; i++){
      gl_lds16(aG[i], As + ldsOff[i]);
      gl_lds16(bG[i], Bs + ldsOff[i]);
      aG[i] += 32; bG[i] += 32;
    }
    __syncthreads();
    bf16x8 af[4], bfr[4];
    #pragma unroll
    for (int t = 0; t < 4; t++){
      af[t]  = *(const bf16x8*)(As + (quad*128 + wm + t*16 + mr)*8);
      bfr[t] = *(const bf16x8*)(Bs + (quad*128 + wn + t*16 + mr)*8);
    }
    #pragma unroll
    for (int mt = 0; mt < 4; mt++)
      #pragma unroll
      for (int nt = 0; nt < 4; nt++)
        acc[mt][nt] = __builtin_amdgcn_mfma_f32_16x16x32_bf16(af[mt], bfr[nt], acc[mt][nt],0,0,0);
    __syncthreads();
  }

  #pragma unroll
  for (int mt = 0; mt < 4; mt++)
    #pragma unroll
    for (int rr = 0; rr < 4; rr++){
      int row = bm + wm + mt*16 + quad*4 + rr;
      float* orow = out + (size_t)row*512;
      #pragma unroll
      for (int nt = 0; nt < 4; nt++){
        int col = bn + wn + nt*16 + mr;
        orow[col] = acc[mt][nt][rr] + biasc[col];
      }
    }
}

// ---------- launch ----------
extern "C" void kernel_launch(void* const* d_in, const int* in_sizes, int n_in,
                              void* d_out, int out_size, void* d_ws, size_t ws_size,
                              hipStream_t stream)
{
  const float* tokens    = (const float*)d_in[0];
  const float* pre_w[4]  = {(const float*)d_in[1], (const float*)d_in[3], (const float*)d_in[5], (const float*)d_in[7]};
  const float* pre_b[4]  = {(const float*)d_in[2], (const float*)d_in[4], (const float*)d_in[6], (const float*)d_in[8]};
  const float* post_w[4] = {(const float*)d_in[9], (const float*)d_in[11], (const float*)d_in[13], (const float*)d_in[15]};
  const float* post_b[4] = {(const float*)d_in[10], (const float*)d_in[12], (const float*)d_in[14], (const float*)d_in[16]};
  const float* in_proj   = (const float*)d_in[17];
  const float* conv_x_w  = (const float*)d_in[18];
  const float* conv_x_b  = (const float*)d_in[19];
  const float* conv_z_w  = (const float*)d_in[20];
  const float* conv_z_b  = (const float*)d_in[21];
  const float* x_proj_w  = (const float*)d_in[22];
  const float* ln_w      = (const float*)d_in[23];
  const float* ln_b      = (const float*)d_in[24];
  const float* dt_proj_w = (const float*)d_in[25];
  const float* dt_proj_b = (const float*)d_in[26];
  const float* A_log     = (const float*)d_in[27];
  const float* D_param   = (const float*)d_in[28];
  const float* out_proj  = (const float*)d_in[29];
  const float* gate_log  = (const float*)d_in[30];

  char* ws = (char*)d_ws;
  size_t o = 0;
  short* tok_bf   = (short*)(ws + o); o += 25690112;   // 12845056 bf16
  short* wpreT    = (short*)(ws + o); o += 2097152;    // 4x 512x512 bf16 (transposed)
  short* inp_bf   = (short*)(ws + o); o += 524288;
  short* postw_bf = (short*)(ws + o); o += 2097152;
  short* woutT    = (short*)(ws + o); o += 524288;
  short* wogc     = (short*)(ws + o); o += 2097152;    // 512 x 2048 bf16
  short* wxz      = (short*)(ws + o); o += 2097152;    // 4x 512x512 bf16
  short* xpw_bf   = (short*)(ws + o); o += 24576;      // 48x256 bf16
  short* dtw_bf   = (short*)(ws + o); o += 16384;      // 256x32 bf16
  float* bxz      = (float*)(ws + o); o += 8192;
  float* gains    = (float*)(ws + o); o += 64;
  float* biasc    = (float*)(ws + o); o += 2048;
  size_t xz_off = o;
  short* xz       = (short*)(ws + o); o += 102760448;  // 2048*49*512 bf16
  short* ycat     = (short*)(ws + o); o += 102760448;  // 25088 x 2048 bf16
  // dtln (51.4 MB) + bc (6.4 MB) alias the xz region: xz is dead after k_conv.
  short* dtln     = (short*)(ws + xz_off);
  float* bc       = (float*)(ws + xz_off + 51380224);

  k_conv_all<<<1300, 256, 0, stream>>>(in_proj,
      post_w[0], post_w[1], post_w[2], post_w[3],
      x_proj_w, dt_proj_w, inp_bf, postw_bf, xpw_bf, dtw_bf);
  k_transp<<<dim3(64,5), 256, 0, stream>>>(pre_w[0], pre_w[1], pre_w[2], pre_w[3],
      out_proj, wpreT, woutT);
  k_tok<<<12544, 256, 0, stream>>>(tokens, tok_bf);
  k_bxz_gains<<<9, 256, 0, stream>>>(in_proj, pre_b[0], pre_b[1], pre_b[2], pre_b[3],
      gate_log, post_b[0], post_b[1], post_b[2], post_b[3], bxz, gains, biasc);
  k_wfuse<<<dim3(8,4,8), 256, 0, stream>>>(inp_bf, wpreT, postw_bf, woutT, gains, wxz, wogc);
  k_gemm1<<<dim3(4,196,4), 256, 0, stream>>>(tok_bf, wxz, bxz, xz);
  k_conv<<<2048, 256, 0, stream>>>(xz, conv_x_w, conv_x_b, conv_z_w, conv_z_b, ycat);
  k_xproj<<<784, 256, 0, stream>>>(ycat, xpw_bf, ln_w, ln_b, dtw_bf, dt_proj_b, dtln, bc);
  k_scan<<<2048, 256, 0, stream>>>(ycat, dtln, bc, A_log, D_param);
  k_gemmF<<<dim3(4,196,1), 256, 0, stream>>>(ycat, wogc, biasc, (float*)d_out);
}